// Round 2
// baseline (452.862 us; speedup 1.0000x reference)
//
#include <hip/hip_runtime.h>

#define T_TOK 2048
#define DIMX  1024
#define AHX   2048
#define HIDX  1024
#define NEXP  8
#define NHEAD 16
#define HD    128

typedef short bf16x8 __attribute__((ext_vector_type(8)));
typedef float f32x4  __attribute__((ext_vector_type(4)));

__device__ __forceinline__ unsigned short f2bf(float f){
  unsigned int u = __builtin_bit_cast(unsigned int, f);
  u += 0x7FFFu + ((u >> 16) & 1u);          // RNE
  return (unsigned short)(u >> 16);
}
__device__ __forceinline__ float bf2f(unsigned short h){
  unsigned int u = ((unsigned int)h) << 16;
  return __builtin_bit_cast(float, u);
}
__device__ __forceinline__ float gelu_exact(float x){
  return 0.5f * x * (1.0f + erff(x * 0.70710678118654752440f));
}

// ---------------- transpose + cast: fp32 [R,C] -> bf16 [C,R] ----------------
__global__ void k_transpose_cast(const float* __restrict__ in,
                                 unsigned short* __restrict__ out, int R, int C){
  __shared__ float tile[32][33];
  int bx = blockIdx.x * 32, by = blockIdx.y * 32;
  int tx = threadIdx.x, ty = threadIdx.y;
  #pragma unroll
  for (int i = 0; i < 32; i += 8)
    tile[ty + i][tx] = in[(size_t)(by + ty + i) * C + bx + tx];
  __syncthreads();
  #pragma unroll
  for (int i = 0; i < 32; i += 8)
    out[(size_t)(bx + ty + i) * R + by + tx] = f2bf(tile[tx][ty + i]);
}

__global__ void k_transpose_cast_split(const float* __restrict__ in,
                                       unsigned short* __restrict__ outh,
                                       unsigned short* __restrict__ outl, int R, int C){
  __shared__ float tile[32][33];
  int bx = blockIdx.x * 32, by = blockIdx.y * 32;
  int tx = threadIdx.x, ty = threadIdx.y;
  #pragma unroll
  for (int i = 0; i < 32; i += 8)
    tile[ty + i][tx] = in[(size_t)(by + ty + i) * C + bx + tx];
  __syncthreads();
  #pragma unroll
  for (int i = 0; i < 32; i += 8){
    float v = tile[tx][ty + i];
    unsigned short h = f2bf(v);
    size_t o = (size_t)(bx + ty + i) * R + by + tx;
    outh[o] = h;
    outl[o] = f2bf(v - bf2f(h));
  }
}

// ---------------- elementwise split: fp32 -> bf16 hi/lo ----------------
__global__ void k_split_cast(const float* __restrict__ in,
                             unsigned short* __restrict__ hi,
                             unsigned short* __restrict__ lo, int n){
  int i = blockIdx.x * 256 + threadIdx.x;
  if (i >= n) return;
  float v = in[i];
  unsigned short h = f2bf(v);
  hi[i] = h;
  lo[i] = f2bf(v - bf2f(h));
}

// ---------------- rmsnorm over rows of [T, AHX], out bf16 ----------------
__global__ __launch_bounds__(256) void k_rmsnorm_rows(const float* __restrict__ in,
                                                      const float* __restrict__ w,
                                                      unsigned short* __restrict__ out){
  int row = blockIdx.x;
  const float* p = in + (size_t)row * AHX;
  int t = threadIdx.x;
  float v[8];
  *(float4*)&v[0] = *(const float4*)(p + t * 8);
  *(float4*)&v[4] = *(const float4*)(p + t * 8 + 4);
  float s = 0.f;
  #pragma unroll
  for (int i = 0; i < 8; i++) s += v[i] * v[i];
  #pragma unroll
  for (int m = 1; m < 64; m <<= 1) s += __shfl_xor(s, m);
  __shared__ float ps[4];
  if ((t & 63) == 0) ps[t >> 6] = s;
  __syncthreads();
  float tot = ps[0] + ps[1] + ps[2] + ps[3];
  float rs = rsqrtf(tot * (1.0f / AHX) + 1e-6f);
  #pragma unroll
  for (int i = 0; i < 8; i++)
    out[(size_t)row * AHX + t * 8 + i] = f2bf(v[i] * rs * w[t * 8 + i]);
}

// ---------------- per-head rmsnorm: fp32 [T,AHX] -> bf16 [T,AHX] ----------------
__global__ __launch_bounds__(64) void k_headnorm(const float* __restrict__ in,
                                                 const float* __restrict__ w,
                                                 unsigned short* __restrict__ out){
  int b = blockIdx.x;
  int row = b >> 4, h = b & 15;
  size_t base = (size_t)row * AHX + h * HD;
  int t = threadIdx.x;
  float v0 = in[base + t], v1 = in[base + t + 64];
  float s = v0 * v0 + v1 * v1;
  #pragma unroll
  for (int m = 1; m < 64; m <<= 1) s += __shfl_xor(s, m);
  float rs = rsqrtf(s * (1.0f / HD) + 1e-6f);
  out[base + t]      = f2bf(v0 * rs * w[t]);
  out[base + t + 64] = f2bf(v1 * rs * w[t + 64]);
}

// ---------------- GEMM: C[M,N] = A[M,K] * B[N,K]^T (+bias, epilogue) ----------------
// EPI 0: store fp32. EPI 1: gelu -> bf16 hi/lo. EPI 2: gelu -> fp32.
// SPLIT: A,B given as hi/lo bf16 pairs; 3-MFMA fp32 emulation.
template<bool SPLIT, int EPI>
__global__ __launch_bounds__(256) void k_gemm_bt(
    const unsigned short* __restrict__ Ah_, const unsigned short* __restrict__ Al_,
    const unsigned short* __restrict__ Bh_, const unsigned short* __restrict__ Bl_,
    const float* __restrict__ bias,
    float* __restrict__ Cf, unsigned short* __restrict__ Ch, unsigned short* __restrict__ Cl,
    int M, int N, int K)
{
  constexpr int LDT = 40;  // 32 + 8 pad (2-way-free LDS banking)
  __shared__ __align__(16) unsigned short sA[128 * LDT];
  __shared__ __align__(16) unsigned short sB[128 * LDT];
  __shared__ __align__(16) unsigned short sAl[SPLIT ? 128 * LDT : 8];
  __shared__ __align__(16) unsigned short sBl[SPLIT ? 128 * LDT : 8];

  int tid = threadIdx.x;
  int bm = blockIdx.y * 128, bn = blockIdx.x * 128;
  int w = tid >> 6, l = tid & 63;
  int wm = (w >> 1) * 64, wn = (w & 1) * 64;
  int lhi = l >> 4, llo = l & 15;

  f32x4 acc[4][4] = {};

  for (int k0 = 0; k0 < K; k0 += 32){
    __syncthreads();
    #pragma unroll
    for (int i = 0; i < 2; i++){
      int chunk = tid + i * 256;
      int r = chunk >> 2;
      int c = (chunk & 3) * 8;
      *(uint4*)&sA[r * LDT + c] = *(const uint4*)&Ah_[(size_t)(bm + r) * K + k0 + c];
      *(uint4*)&sB[r * LDT + c] = *(const uint4*)&Bh_[(size_t)(bn + r) * K + k0 + c];
      if constexpr (SPLIT){
        *(uint4*)&sAl[r * LDT + c] = *(const uint4*)&Al_[(size_t)(bm + r) * K + k0 + c];
        *(uint4*)&sBl[r * LDT + c] = *(const uint4*)&Bl_[(size_t)(bn + r) * K + k0 + c];
      }
    }
    __syncthreads();
    bf16x8 af[4], bfr[4], afl[4], bfl[4];
    #pragma unroll
    for (int m = 0; m < 4; m++){
      af[m]  = *(const bf16x8*)&sA[(wm + m * 16 + llo) * LDT + lhi * 8];
      bfr[m] = *(const bf16x8*)&sB[(wn + m * 16 + llo) * LDT + lhi * 8];
      if constexpr (SPLIT){
        afl[m] = *(const bf16x8*)&sAl[(wm + m * 16 + llo) * LDT + lhi * 8];
        bfl[m] = *(const bf16x8*)&sBl[(wn + m * 16 + llo) * LDT + lhi * 8];
      }
    }
    #pragma unroll
    for (int m = 0; m < 4; m++){
      #pragma unroll
      for (int n = 0; n < 4; n++){
        acc[m][n] = __builtin_amdgcn_mfma_f32_16x16x32_bf16(af[m], bfr[n], acc[m][n], 0, 0, 0);
        if constexpr (SPLIT){
          acc[m][n] = __builtin_amdgcn_mfma_f32_16x16x32_bf16(af[m],  bfl[n], acc[m][n], 0, 0, 0);
          acc[m][n] = __builtin_amdgcn_mfma_f32_16x16x32_bf16(afl[m], bfr[n], acc[m][n], 0, 0, 0);
        }
      }
    }
  }
  #pragma unroll
  for (int m = 0; m < 4; m++){
    #pragma unroll
    for (int n = 0; n < 4; n++){
      int col = bn + wn + n * 16 + llo;
      float bv = bias[col];
      #pragma unroll
      for (int j = 0; j < 4; j++){
        int row = bm + wm + m * 16 + lhi * 4 + j;
        float v = acc[m][n][j] + bv;
        size_t off = (size_t)row * N + col;
        if constexpr (EPI == 0){
          Cf[off] = v;
        } else if constexpr (EPI == 1){
          float g = gelu_exact(v);
          unsigned short hh = f2bf(g);
          Ch[off] = hh;
          Cl[off] = f2bf(g - bf2f(hh));
        } else {
          Cf[off] = gelu_exact(v);
        }
      }
    }
  }
}

// ---------------- scores pass 1: per-row max m and denom Z ----------------
__global__ __launch_bounds__(256) void k_scores_pass1(const unsigned short* __restrict__ Qn,
                                                      const unsigned short* __restrict__ Kn,
                                                      float* __restrict__ m_ws,
                                                      float* __restrict__ z_ws){
  constexpr int LDK = 136;  // 128 + 8 pad
  __shared__ __align__(16) unsigned short sK[128 * LDK];
  int h = blockIdx.y;
  int qb = blockIdx.x * 128;
  int tid = threadIdx.x, w = tid >> 6, l = tid & 63;
  int lhi = l >> 4, llo = l & 15;
  int wq = qb + w * 32;
  const float scale = 0.08838834764831845f;  // 1/sqrt(128)

  bf16x8 qf[2][4];
  #pragma unroll
  for (int m = 0; m < 2; m++)
    #pragma unroll
    for (int ks = 0; ks < 4; ks++)
      qf[m][ks] = *(const bf16x8*)&Qn[(size_t)(wq + m * 16 + llo) * AHX + h * HD + ks * 32 + lhi * 8];

  float rm[2][4], rz[2][4];
  #pragma unroll
  for (int m = 0; m < 2; m++)
    #pragma unroll
    for (int j = 0; j < 4; j++){ rm[m][j] = -__builtin_inff(); rz[m][j] = 0.f; }

  for (int kt = 0; kt < T_TOK; kt += 128){
    __syncthreads();
    #pragma unroll
    for (int i = 0; i < 8; i++){
      int chunk = tid + i * 256;
      int r = chunk >> 4, c = (chunk & 15) * 8;
      *(uint4*)&sK[r * LDK + c] = *(const uint4*)&Kn[(size_t)(kt + r) * AHX + h * HD + c];
    }
    __syncthreads();
    f32x4 acc[2][8] = {};
    #pragma unroll
    for (int n = 0; n < 8; n++){
      #pragma unroll
      for (int ks = 0; ks < 4; ks++){
        bf16x8 kf = *(const bf16x8*)&sK[(n * 16 + llo) * LDK + ks * 32 + lhi * 8];
        acc[0][n] = __builtin_amdgcn_mfma_f32_16x16x32_bf16(qf[0][ks], kf, acc[0][n], 0, 0, 0);
        acc[1][n] = __builtin_amdgcn_mfma_f32_16x16x32_bf16(qf[1][ks], kf, acc[1][n], 0, 0, 0);
      }
    }
    #pragma unroll
    for (int m = 0; m < 2; m++){
      #pragma unroll
      for (int j = 0; j < 4; j++){
        float mx = acc[m][0][j];
        #pragma unroll
        for (int n = 1; n < 8; n++) mx = fmaxf(mx, acc[m][n][j]);
        mx *= scale;
        mx = fmaxf(mx, __shfl_xor(mx, 1));
        mx = fmaxf(mx, __shfl_xor(mx, 2));
        mx = fmaxf(mx, __shfl_xor(mx, 4));
        mx = fmaxf(mx, __shfl_xor(mx, 8));
        float newm = fmaxf(rm[m][j], mx);
        float sum = 0.f;
        #pragma unroll
        for (int n = 0; n < 8; n++) sum += __expf(acc[m][n][j] * scale - newm);
        sum += __shfl_xor(sum, 1);
        sum += __shfl_xor(sum, 2);
        sum += __shfl_xor(sum, 4);
        sum += __shfl_xor(sum, 8);
        rz[m][j] = rz[m][j] * __expf(rm[m][j] - newm) + sum;
        rm[m][j] = newm;
      }
    }
  }
  if (llo == 0){
    #pragma unroll
    for (int m = 0; m < 2; m++)
      #pragma unroll
      for (int j = 0; j < 4; j++){
        int row = wq + m * 16 + lhi * 4 + j;
        m_ws[h * T_TOK + row] = rm[m][j];
        z_ws[h * T_TOK + row] = rz[m][j];
      }
  }
}

// ---------------- scores pass 2: column sums of exp(s-m)/Z/NHEAD ----------------
__global__ __launch_bounds__(256) void k_scores_pass2(const unsigned short* __restrict__ Qn,
                                                      const unsigned short* __restrict__ Kn,
                                                      const float* __restrict__ m_ws,
                                                      const float* __restrict__ z_ws,
                                                      float* __restrict__ imp){
  constexpr int LDK = 136;
  __shared__ __align__(16) unsigned short sK[128 * LDK];
  __shared__ float simp[128];
  int h = blockIdx.y;
  int qb = blockIdx.x * 128;
  int tid = threadIdx.x, w = tid >> 6, l = tid & 63;
  int lhi = l >> 4, llo = l & 15;
  int wq = qb + w * 32;
  const float scale = 0.08838834764831845f;

  bf16x8 qf[2][4];
  #pragma unroll
  for (int m = 0; m < 2; m++)
    #pragma unroll
    for (int ks = 0; ks < 4; ks++)
      qf[m][ks] = *(const bf16x8*)&Qn[(size_t)(wq + m * 16 + llo) * AHX + h * HD + ks * 32 + lhi * 8];

  float rm[2][4], rc[2][4];
  #pragma unroll
  for (int m = 0; m < 2; m++)
    #pragma unroll
    for (int j = 0; j < 4; j++){
      int row = wq + m * 16 + lhi * 4 + j;
      rm[m][j] = m_ws[h * T_TOK + row];
      rc[m][j] = 1.0f / ((float)NHEAD * z_ws[h * T_TOK + row]);
    }

  for (int kt = 0; kt < T_TOK; kt += 128){
    __syncthreads();
    if (tid < 128) simp[tid] = 0.f;
    #pragma unroll
    for (int i = 0; i < 8; i++){
      int chunk = tid + i * 256;
      int r = chunk >> 4, c = (chunk & 15) * 8;
      *(uint4*)&sK[r * LDK + c] = *(const uint4*)&Kn[(size_t)(kt + r) * AHX + h * HD + c];
    }
    __syncthreads();
    f32x4 acc[2][8] = {};
    #pragma unroll
    for (int n = 0; n < 8; n++){
      #pragma unroll
      for (int ks = 0; ks < 4; ks++){
        bf16x8 kf = *(const bf16x8*)&sK[(n * 16 + llo) * LDK + ks * 32 + lhi * 8];
        acc[0][n] = __builtin_amdgcn_mfma_f32_16x16x32_bf16(qf[0][ks], kf, acc[0][n], 0, 0, 0);
        acc[1][n] = __builtin_amdgcn_mfma_f32_16x16x32_bf16(qf[1][ks], kf, acc[1][n], 0, 0, 0);
      }
    }
    #pragma unroll
    for (int n = 0; n < 8; n++){
      float s = 0.f;
      #pragma unroll
      for (int m = 0; m < 2; m++)
        #pragma unroll
        for (int j = 0; j < 4; j++)
          s += __expf(acc[m][n][j] * scale - rm[m][j]) * rc[m][j];
      s += __shfl_xor(s, 16);
      s += __shfl_xor(s, 32);
      if (l < 16) atomicAdd(&simp[n * 16 + l], s);
    }
    __syncthreads();
    if (tid < 128) atomicAdd(&imp[kt + tid], simp[tid]);
  }
}

// ---------------- router: logits, softmax, grouped top-k ----------------
__global__ __launch_bounds__(256) void k_router(const float* __restrict__ h2,
                                                const float* __restrict__ w3,
                                                const float* __restrict__ b3,
                                                float* __restrict__ out){
  int t = blockIdx.x * 4 + (threadIdx.x >> 6);
  int l = threadIdx.x & 63;
  const float* hp = h2 + (size_t)t * HIDX;
  float acc[NEXP] = {};
  for (int i = l; i < HIDX; i += 64){
    float hv = hp[i];
    const float* wr = w3 + (size_t)i * NEXP;
    #pragma unroll
    for (int e = 0; e < NEXP; e++) acc[e] = fmaf(hv, wr[e], acc[e]);
  }
  #pragma unroll
  for (int mk = 1; mk < 64; mk <<= 1)
    #pragma unroll
    for (int e = 0; e < NEXP; e++) acc[e] += __shfl_xor(acc[e], mk);
  if (l == 0){
    float lg[NEXP], mx = -__builtin_inff();
    #pragma unroll
    for (int e = 0; e < NEXP; e++){ lg[e] = acc[e] + b3[e]; mx = fmaxf(mx, lg[e]); }
    float Z = 0.f, p[NEXP];
    #pragma unroll
    for (int e = 0; e < NEXP; e++){ p[e] = expf(lg[e] - mx); Z += p[e]; }
    float invZ = 1.0f / Z;
    #pragma unroll
    for (int e = 0; e < NEXP; e++) p[e] *= invZ;
    float gs[4];
    #pragma unroll
    for (int g = 0; g < 4; g++) gs[g] = fmaxf(p[2 * g], p[2 * g + 1]);
    int g1 = 0;
    #pragma unroll
    for (int g = 1; g < 4; g++) if (gs[g] > gs[g1]) g1 = g;
    int g2 = -1; float g2v = -__builtin_inff();
    #pragma unroll
    for (int g = 0; g < 4; g++) if (g != g1 && gs[g] > g2v){ g2v = gs[g]; g2 = g; }
    int best = 0; float bv = -__builtin_inff();
    #pragma unroll
    for (int e = 0; e < NEXP; e++){
      int g = e >> 1;
      if ((g == g1 || g == g2) && p[e] > bv){ bv = p[e]; best = e; }
    }
    out[t]         = bv;            // ROUTE_SCALE = 1.0
    out[T_TOK + t] = (float)best;   // idx as float
  }
}

// ---------------- driver ----------------
extern "C" void kernel_launch(void* const* d_in, const int* in_sizes, int n_in,
                              void* d_out, int out_size, void* d_ws, size_t ws_size,
                              hipStream_t stream){
  const float* x     = (const float*)d_in[0];
  const float* xproj = (const float*)d_in[1];
  const float* anw   = (const float*)d_in[2];
  const float* wq    = (const float*)d_in[3];
  const float* bq    = (const float*)d_in[4];
  const float* wk    = (const float*)d_in[5];
  const float* bk    = (const float*)d_in[6];
  const float* qnw   = (const float*)d_in[7];
  const float* knw   = (const float*)d_in[8];
  const float* w1    = (const float*)d_in[9];
  const float* b1    = (const float*)d_in[10];
  const float* w2    = (const float*)d_in[11];
  const float* b2    = (const float*)d_in[12];
  const float* w3    = (const float*)d_in[13];
  const float* b3    = (const float*)d_in[14];
  float* out = (float*)d_out;

  char* ws = (char*)d_ws;
  const size_t MB = 1024 * 1024;
  // peak ws use: 89 MB
  unsigned short* xn   = (unsigned short*)(ws);             // 8MB  bf16 [T,AH]
  unsigned short* wqT  = (unsigned short*)(ws + 8 * MB);    // 8MB  bf16 [2048,2048]
  unsigned short* wkT  = (unsigned short*)(ws + 16 * MB);   // 8MB
  float* Qf            = (float*)(ws + 24 * MB);            // 16MB (reused by h1/h2 later)
  float* Kf            = (float*)(ws + 40 * MB);            // 16MB
  unsigned short* Qnn  = (unsigned short*)(ws + 56 * MB);   // 8MB
  unsigned short* Knn  = (unsigned short*)(ws + 64 * MB);   // 8MB
  float* m_ws          = (float*)(ws + 72 * MB);            // 128KB
  float* z_ws          = (float*)(ws + 72 * MB + 256 * 1024);
  unsigned short* xh   = (unsigned short*)(ws + 73 * MB);   // 4MB
  unsigned short* xl   = (unsigned short*)(ws + 77 * MB);   // 4MB
  unsigned short* w1Th = (unsigned short*)(ws + 81 * MB);   // 2MB
  unsigned short* w1Tl = (unsigned short*)(ws + 83 * MB);
  unsigned short* w2Th = (unsigned short*)(ws + 85 * MB);
  unsigned short* w2Tl = (unsigned short*)(ws + 87 * MB);
  // MLP activations overlap dead Qf region (MLP runs after headnorm):
  unsigned short* h1h  = (unsigned short*)(ws + 24 * MB);   // 4MB
  unsigned short* h1l  = (unsigned short*)(ws + 28 * MB);   // 4MB
  float* h2            = (float*)(ws + 32 * MB);            // 8MB

  // zero importance region of d_out (floats [2T, 3T))
  hipMemsetAsync((char*)d_out + (size_t)2 * T_TOK * 4, 0, (size_t)T_TOK * 4, stream);

  dim3 tb(32, 8);
  k_transpose_cast<<<dim3(AHX / 32, AHX / 32), tb, 0, stream>>>(wq, wqT, AHX, AHX);
  k_transpose_cast<<<dim3(AHX / 32, AHX / 32), tb, 0, stream>>>(wk, wkT, AHX, AHX);
  k_transpose_cast_split<<<dim3(HIDX / 32, DIMX / 32), tb, 0, stream>>>(w1, w1Th, w1Tl, DIMX, HIDX);
  k_transpose_cast_split<<<dim3(HIDX / 32, HIDX / 32), tb, 0, stream>>>(w2, w2Th, w2Tl, HIDX, HIDX);
  k_split_cast<<<(T_TOK * DIMX) / 256, 256, 0, stream>>>(x, xh, xl, T_TOK * DIMX);
  k_rmsnorm_rows<<<T_TOK, 256, 0, stream>>>(xproj, anw, xn);

  // Q/K projections (bf16 MFMA), then per-head rmsnorm -> bf16
  k_gemm_bt<false, 0><<<dim3(16, 16), 256, 0, stream>>>(xn, nullptr, wqT, nullptr, bq,
                                                        Qf, nullptr, nullptr, T_TOK, AHX, AHX);
  k_gemm_bt<false, 0><<<dim3(16, 16), 256, 0, stream>>>(xn, nullptr, wkT, nullptr, bk,
                                                        Kf, nullptr, nullptr, T_TOK, AHX, AHX);
  k_headnorm<<<T_TOK * NHEAD, 64, 0, stream>>>(Qf, qnw, Qnn);
  k_headnorm<<<T_TOK * NHEAD, 64, 0, stream>>>(Kf, knw, Knn);

  // two-pass softmax column-sum (importance)
  k_scores_pass1<<<dim3(16, 16), 256, 0, stream>>>(Qnn, Knn, m_ws, z_ws);
  k_scores_pass2<<<dim3(16, 16), 256, 0, stream>>>(Qnn, Knn, m_ws, z_ws, out + 2 * T_TOK);

  // router MLP (split-bf16 fp32 emulation) + routing
  k_gemm_bt<true, 1><<<dim3(HIDX / 128, T_TOK / 128), 256, 0, stream>>>(
      xh, xl, w1Th, w1Tl, b1, nullptr, h1h, h1l, T_TOK, HIDX, DIMX);
  k_gemm_bt<true, 2><<<dim3(HIDX / 128, T_TOK / 128), 256, 0, stream>>>(
      h1h, h1l, w2Th, w2Tl, b2, h2, nullptr, nullptr, T_TOK, HIDX, HIDX);
  k_router<<<T_TOK / 4, 256, 0, stream>>>(h2, w3, b3, out);

  (void)in_sizes; (void)n_in; (void)out_size; (void)ws_size;
}

// Round 3
// 273.972 us; speedup vs baseline: 1.6530x; 1.6530x over previous
//
#include <hip/hip_runtime.h>

#define T_TOK 2048
#define DIMX  1024
#define AHX   2048
#define HIDX  1024
#define NEXP  8
#define NHEAD 16
#define HD    128

typedef short bf16x8 __attribute__((ext_vector_type(8)));
typedef float f32x4  __attribute__((ext_vector_type(4)));

__device__ __forceinline__ unsigned short f2bf(float f){
  unsigned int u = __builtin_bit_cast(unsigned int, f);
  u += 0x7FFFu + ((u >> 16) & 1u);          // RNE
  return (unsigned short)(u >> 16);
}
__device__ __forceinline__ float bf2f(unsigned short h){
  unsigned int u = ((unsigned int)h) << 16;
  return __builtin_bit_cast(float, u);
}
__device__ __forceinline__ float gelu_exact(float x){
  return 0.5f * x * (1.0f + erff(x * 0.70710678118654752440f));
}
__device__ __forceinline__ void gload16(const unsigned short* g, unsigned short* l){
  __builtin_amdgcn_global_load_lds((const __attribute__((address_space(1))) unsigned int*)g,
                                   (__attribute__((address_space(3))) unsigned int*)l, 16, 0, 0);
}

// ---------------- transpose + cast: fp32 [R,C] -> bf16 [C,R] ----------------
__global__ void k_transpose_cast(const float* __restrict__ in,
                                 unsigned short* __restrict__ out, int R, int C){
  __shared__ float tile[32][33];
  int bx = blockIdx.x * 32, by = blockIdx.y * 32;
  int tx = threadIdx.x, ty = threadIdx.y;
  #pragma unroll
  for (int i = 0; i < 32; i += 8)
    tile[ty + i][tx] = in[(size_t)(by + ty + i) * C + bx + tx];
  __syncthreads();
  #pragma unroll
  for (int i = 0; i < 32; i += 8)
    out[(size_t)(bx + ty + i) * R + by + tx] = f2bf(tile[tx][ty + i]);
}

__global__ void k_transpose_cast_split(const float* __restrict__ in,
                                       unsigned short* __restrict__ outh,
                                       unsigned short* __restrict__ outl, int R, int C){
  __shared__ float tile[32][33];
  int bx = blockIdx.x * 32, by = blockIdx.y * 32;
  int tx = threadIdx.x, ty = threadIdx.y;
  #pragma unroll
  for (int i = 0; i < 32; i += 8)
    tile[ty + i][tx] = in[(size_t)(by + ty + i) * C + bx + tx];
  __syncthreads();
  #pragma unroll
  for (int i = 0; i < 32; i += 8){
    float v = tile[tx][ty + i];
    unsigned short h = f2bf(v);
    size_t o = (size_t)(bx + ty + i) * R + by + tx;
    outh[o] = h;
    outl[o] = f2bf(v - bf2f(h));
  }
}

__global__ void k_split_cast(const float* __restrict__ in,
                             unsigned short* __restrict__ hi,
                             unsigned short* __restrict__ lo, int n){
  int i = blockIdx.x * 256 + threadIdx.x;
  if (i >= n) return;
  float v = in[i];
  unsigned short h = f2bf(v);
  hi[i] = h;
  lo[i] = f2bf(v - bf2f(h));
}

// ---------------- rmsnorm over rows of [T, AHX], out bf16 ----------------
__global__ __launch_bounds__(256) void k_rmsnorm_rows(const float* __restrict__ in,
                                                      const float* __restrict__ w,
                                                      unsigned short* __restrict__ out){
  int row = blockIdx.x;
  const float* p = in + (size_t)row * AHX;
  int t = threadIdx.x;
  float v[8];
  *(float4*)&v[0] = *(const float4*)(p + t * 8);
  *(float4*)&v[4] = *(const float4*)(p + t * 8 + 4);
  float s = 0.f;
  #pragma unroll
  for (int i = 0; i < 8; i++) s += v[i] * v[i];
  #pragma unroll
  for (int m = 1; m < 64; m <<= 1) s += __shfl_xor(s, m);
  __shared__ float ps[4];
  if ((t & 63) == 0) ps[t >> 6] = s;
  __syncthreads();
  float tot = ps[0] + ps[1] + ps[2] + ps[3];
  float rs = rsqrtf(tot * (1.0f / AHX) + 1e-6f);
  #pragma unroll
  for (int i = 0; i < 8; i++)
    out[(size_t)row * AHX + t * 8 + i] = f2bf(v[i] * rs * w[t * 8 + i]);
}

// ---------------- per-head rmsnorm: fp32 [T,in_stride] -> bf16 [T,2048] ----------------
__global__ __launch_bounds__(64) void k_headnorm(const float* __restrict__ in,
                                                 const float* __restrict__ w,
                                                 unsigned short* __restrict__ out,
                                                 int in_stride){
  int b = blockIdx.x;
  int row = b >> 4, h = b & 15;
  size_t bi = (size_t)row * in_stride + h * HD;
  size_t bo = (size_t)row * AHX + h * HD;
  int t = threadIdx.x;
  float v0 = in[bi + t], v1 = in[bi + t + 64];
  float s = v0 * v0 + v1 * v1;
  #pragma unroll
  for (int m = 1; m < 64; m <<= 1) s += __shfl_xor(s, m);
  float rs = rsqrtf(s * (1.0f / HD) + 1e-6f);
  out[bo + t]      = f2bf(v0 * rs * w[t]);
  out[bo + t + 64] = f2bf(v1 * rs * w[t + 64]);
}

// ---------------- fused Q+K projection GEMM: C[M,N] = A[M,K]*B[N,K]^T + bias ----------------
// m97 structure: global_load_lds width 16, linear [128][32] LDS.
__global__ __launch_bounds__(256) void k_gemm_qk(
    const unsigned short* __restrict__ A, const unsigned short* __restrict__ B,
    const float* __restrict__ bias, float* __restrict__ C, int M, int N, int K)
{
  __shared__ __align__(16) unsigned short sA[128 * 32];
  __shared__ __align__(16) unsigned short sB[128 * 32];
  int tid = threadIdx.x;
  int bm = blockIdx.y * 128, bn = blockIdx.x * 128;
  int w = tid >> 6, l = tid & 63;
  int wm = (w >> 1) * 64, wn = (w & 1) * 64;
  int lhi = l >> 4, llo = l & 15;
  int rA = l >> 2, cA = (l & 3) * 8;

  f32x4 acc[4][4] = {};

  for (int k0 = 0; k0 < K; k0 += 32){
    __syncthreads();
    #pragma unroll
    for (int i = 0; i < 2; i++){
      int rb = w * 32 + i * 16;                   // wave-uniform row base
      gload16(&A[(size_t)(bm + rb + rA) * K + k0 + cA], &sA[rb * 32]);
      gload16(&B[(size_t)(bn + rb + rA) * K + k0 + cA], &sB[rb * 32]);
    }
    __syncthreads();
    bf16x8 af[4], bfr[4];
    #pragma unroll
    for (int m = 0; m < 4; m++){
      af[m]  = *(const bf16x8*)&sA[(wm + m * 16 + llo) * 32 + lhi * 8];
      bfr[m] = *(const bf16x8*)&sB[(wn + m * 16 + llo) * 32 + lhi * 8];
    }
    #pragma unroll
    for (int m = 0; m < 4; m++)
      #pragma unroll
      for (int n = 0; n < 4; n++)
        acc[m][n] = __builtin_amdgcn_mfma_f32_16x16x32_bf16(af[m], bfr[n], acc[m][n], 0, 0, 0);
  }
  #pragma unroll
  for (int m = 0; m < 4; m++)
    #pragma unroll
    for (int n = 0; n < 4; n++){
      int col = bn + wn + n * 16 + llo;
      float bv = bias[col];
      #pragma unroll
      for (int j = 0; j < 4; j++){
        int row = bm + wm + m * 16 + lhi * 4 + j;
        C[(size_t)row * N + col] = acc[m][n][j] + bv;
      }
    }
}

// ---------------- MLP GEMM: C = A*B^T (+bias, epilogue), split-bf16 fp32 emulation ----------
// BM=64 tile (grid 2x): EPI 1: gelu -> bf16 hi/lo. EPI 2: gelu -> fp32.
template<int BM, int EPI>
__global__ __launch_bounds__(256) void k_gemm_bt(
    const unsigned short* __restrict__ Ah_, const unsigned short* __restrict__ Al_,
    const unsigned short* __restrict__ Bh_, const unsigned short* __restrict__ Bl_,
    const float* __restrict__ bias,
    float* __restrict__ Cf, unsigned short* __restrict__ Ch, unsigned short* __restrict__ Cl,
    int M, int N, int K)
{
  constexpr int LDT = 40;
  constexpr int MR = BM / 32;
  __shared__ __align__(16) unsigned short sA[BM * LDT];
  __shared__ __align__(16) unsigned short sB[128 * LDT];
  __shared__ __align__(16) unsigned short sAl[BM * LDT];
  __shared__ __align__(16) unsigned short sBl[128 * LDT];

  int tid = threadIdx.x;
  int bm = blockIdx.y * BM, bn = blockIdx.x * 128;
  int w = tid >> 6, l = tid & 63;
  int wm = (w >> 1) * (MR * 16), wn = (w & 1) * 64;
  int lhi = l >> 4, llo = l & 15;

  f32x4 acc[MR][4] = {};

  for (int k0 = 0; k0 < K; k0 += 32){
    __syncthreads();
    #pragma unroll
    for (int i = 0; i < BM / 64; i++){
      int chunk = tid + i * 256;
      int r = chunk >> 2, c = (chunk & 3) * 8;
      *(uint4*)&sA[r * LDT + c]  = *(const uint4*)&Ah_[(size_t)(bm + r) * K + k0 + c];
      *(uint4*)&sAl[r * LDT + c] = *(const uint4*)&Al_[(size_t)(bm + r) * K + k0 + c];
    }
    #pragma unroll
    for (int i = 0; i < 2; i++){
      int chunk = tid + i * 256;
      int r = chunk >> 2, c = (chunk & 3) * 8;
      *(uint4*)&sB[r * LDT + c]  = *(const uint4*)&Bh_[(size_t)(bn + r) * K + k0 + c];
      *(uint4*)&sBl[r * LDT + c] = *(const uint4*)&Bl_[(size_t)(bn + r) * K + k0 + c];
    }
    __syncthreads();
    bf16x8 af[MR], afl[MR], bfr[4], bfl[4];
    #pragma unroll
    for (int m = 0; m < MR; m++){
      af[m]  = *(const bf16x8*)&sA[(wm + m * 16 + llo) * LDT + lhi * 8];
      afl[m] = *(const bf16x8*)&sAl[(wm + m * 16 + llo) * LDT + lhi * 8];
    }
    #pragma unroll
    for (int n = 0; n < 4; n++){
      bfr[n] = *(const bf16x8*)&sB[(wn + n * 16 + llo) * LDT + lhi * 8];
      bfl[n] = *(const bf16x8*)&sBl[(wn + n * 16 + llo) * LDT + lhi * 8];
    }
    #pragma unroll
    for (int m = 0; m < MR; m++)
      #pragma unroll
      for (int n = 0; n < 4; n++){
        acc[m][n] = __builtin_amdgcn_mfma_f32_16x16x32_bf16(af[m],  bfr[n], acc[m][n], 0, 0, 0);
        acc[m][n] = __builtin_amdgcn_mfma_f32_16x16x32_bf16(af[m],  bfl[n], acc[m][n], 0, 0, 0);
        acc[m][n] = __builtin_amdgcn_mfma_f32_16x16x32_bf16(afl[m], bfr[n], acc[m][n], 0, 0, 0);
      }
  }
  #pragma unroll
  for (int m = 0; m < MR; m++)
    #pragma unroll
    for (int n = 0; n < 4; n++){
      int col = bn + wn + n * 16 + llo;
      float bv = bias[col];
      #pragma unroll
      for (int j = 0; j < 4; j++){
        int row = bm + wm + m * 16 + lhi * 4 + j;
        float v = acc[m][n][j] + bv;
        size_t off = (size_t)row * N + col;
        if constexpr (EPI == 1){
          float g = gelu_exact(v);
          unsigned short hh = f2bf(g);
          Ch[off] = hh;
          Cl[off] = f2bf(g - bf2f(hh));
        } else {
          Cf[off] = gelu_exact(v);
        }
      }
    }
}

// ---------------- scores denominator: zpart[ks][h][row] = sum_k exp(s) over K-chunk --------
__global__ __launch_bounds__(256) void k_z(const unsigned short* __restrict__ Qn,
                                           const unsigned short* __restrict__ Kn,
                                           float* __restrict__ zpart){
  __shared__ __align__(16) unsigned short sK[128 * 128];
  int h = blockIdx.y;
  int qb = blockIdx.x * 128;
  int tid = threadIdx.x, w = tid >> 6, l = tid & 63;
  int lhi = l >> 4, llo = l & 15;
  int wq = qb + w * 32;
  const float scale = 0.08838834764831845f;

  bf16x8 qf[2][4];
  #pragma unroll
  for (int m = 0; m < 2; m++)
    #pragma unroll
    for (int kk = 0; kk < 4; kk++)
      qf[m][kk] = *(const bf16x8*)&Qn[(size_t)(wq + m * 16 + llo) * AHX + h * HD + kk * 32 + lhi * 8];

  float rz[2][4] = {};

  for (int t = 0; t < 2; t++){
    int kt = blockIdx.z * 256 + t * 128;
    __syncthreads();
    #pragma unroll
    for (int i = 0; i < 8; i++){
      int chunk = tid + i * 256;
      int r = chunk >> 4, c = (chunk & 15) * 8;
      *(uint4*)&sK[r * 128 + (c ^ ((r & 7) << 3))] =
          *(const uint4*)&Kn[(size_t)(kt + r) * AHX + h * HD + c];
    }
    __syncthreads();
    f32x4 acc[2][8] = {};
    #pragma unroll
    for (int n = 0; n < 8; n++){
      int row = n * 16 + llo;
      #pragma unroll
      for (int kk = 0; kk < 4; kk++){
        bf16x8 kf = *(const bf16x8*)&sK[row * 128 + ((kk * 32 + lhi * 8) ^ ((llo & 7) << 3))];
        acc[0][n] = __builtin_amdgcn_mfma_f32_16x16x32_bf16(qf[0][kk], kf, acc[0][n], 0, 0, 0);
        acc[1][n] = __builtin_amdgcn_mfma_f32_16x16x32_bf16(qf[1][kk], kf, acc[1][n], 0, 0, 0);
      }
    }
    #pragma unroll
    for (int m = 0; m < 2; m++)
      #pragma unroll
      for (int j = 0; j < 4; j++){
        float s = 0.f;
        #pragma unroll
        for (int n = 0; n < 8; n++) s += __expf(acc[m][n][j] * scale);
        rz[m][j] += s;
      }
  }
  #pragma unroll
  for (int m = 0; m < 2; m++)
    #pragma unroll
    for (int j = 0; j < 4; j++){
      float s = rz[m][j];
      s += __shfl_xor(s, 1); s += __shfl_xor(s, 2);
      s += __shfl_xor(s, 4); s += __shfl_xor(s, 8);
      if (llo == 0){
        int row = wq + m * 16 + lhi * 4 + j;
        zpart[(size_t)blockIdx.z * (NHEAD * T_TOK) + h * T_TOK + row] = s;
      }
    }
}

// ---------------- rc[h][row] = 1/(NHEAD * Z) ----------------
__global__ void k_rc(const float* __restrict__ zpart, float* __restrict__ rc){
  int i = blockIdx.x * 256 + threadIdx.x;   // NHEAD*T_TOK = 32768
  float s = 0.f;
  #pragma unroll
  for (int p = 0; p < 8; p++) s += zpart[p * (NHEAD * T_TOK) + i];
  rc[i] = 1.0f / ((float)NHEAD * s);
}

// ---------------- importance partials: one 128x128 tile per block ----------------
__global__ __launch_bounds__(256) void k_imp(const unsigned short* __restrict__ Qn,
                                             const unsigned short* __restrict__ Kn,
                                             const float* __restrict__ rc,
                                             float* __restrict__ imp_part){
  __shared__ __align__(16) unsigned short sK[128 * 128];
  __shared__ float simp[4][128];
  int h = blockIdx.y;
  int qb = blockIdx.x * 128;
  int kt = blockIdx.z * 128;
  int tid = threadIdx.x, w = tid >> 6, l = tid & 63;
  int lhi = l >> 4, llo = l & 15;
  int wq = qb + w * 32;
  const float scale = 0.08838834764831845f;

  bf16x8 qf[2][4];
  float rcv[2][4];
  #pragma unroll
  for (int m = 0; m < 2; m++)
    #pragma unroll
    for (int kk = 0; kk < 4; kk++)
      qf[m][kk] = *(const bf16x8*)&Qn[(size_t)(wq + m * 16 + llo) * AHX + h * HD + kk * 32 + lhi * 8];
  #pragma unroll
  for (int m = 0; m < 2; m++)
    #pragma unroll
    for (int j = 0; j < 4; j++)
      rcv[m][j] = rc[h * T_TOK + wq + m * 16 + lhi * 4 + j];

  #pragma unroll
  for (int i = 0; i < 8; i++){
    int chunk = tid + i * 256;
    int r = chunk >> 4, c = (chunk & 15) * 8;
    *(uint4*)&sK[r * 128 + (c ^ ((r & 7) << 3))] =
        *(const uint4*)&Kn[(size_t)(kt + r) * AHX + h * HD + c];
  }
  __syncthreads();
  f32x4 acc[2][8] = {};
  #pragma unroll
  for (int n = 0; n < 8; n++){
    int row = n * 16 + llo;
    #pragma unroll
    for (int kk = 0; kk < 4; kk++){
      bf16x8 kf = *(const bf16x8*)&sK[row * 128 + ((kk * 32 + lhi * 8) ^ ((llo & 7) << 3))];
      acc[0][n] = __builtin_amdgcn_mfma_f32_16x16x32_bf16(qf[0][kk], kf, acc[0][n], 0, 0, 0);
      acc[1][n] = __builtin_amdgcn_mfma_f32_16x16x32_bf16(qf[1][kk], kf, acc[1][n], 0, 0, 0);
    }
  }
  #pragma unroll
  for (int n = 0; n < 8; n++){
    float s = 0.f;
    #pragma unroll
    for (int m = 0; m < 2; m++)
      #pragma unroll
      for (int j = 0; j < 4; j++)
        s += __expf(acc[m][n][j] * scale) * rcv[m][j];
    s += __shfl_xor(s, 16);
    s += __shfl_xor(s, 32);
    if (l < 16) simp[w][n * 16 + l] = s;
  }
  __syncthreads();
  if (tid < 128){
    float tot = simp[0][tid] + simp[1][tid] + simp[2][tid] + simp[3][tid];
    imp_part[((size_t)blockIdx.x * NHEAD + h) * T_TOK + kt + tid] = tot;
  }
}

// ---------------- importance reduction over 256 partial rows ----------------
__global__ void k_impred(const float* __restrict__ imp_part, float* __restrict__ imp){
  int col = blockIdx.x * 256 + threadIdx.x;
  float s = 0.f;
  for (int r = 0; r < 256; r++) s += imp_part[(size_t)r * T_TOK + col];
  imp[col] = s;
}

// ---------------- router: logits, softmax, grouped top-k ----------------
__global__ __launch_bounds__(256) void k_router(const float* __restrict__ h2,
                                                const float* __restrict__ w3,
                                                const float* __restrict__ b3,
                                                float* __restrict__ out){
  int t = blockIdx.x * 4 + (threadIdx.x >> 6);
  int l = threadIdx.x & 63;
  const float* hp = h2 + (size_t)t * HIDX;
  float acc[NEXP] = {};
  for (int i = l; i < HIDX; i += 64){
    float hv = hp[i];
    const float* wr = w3 + (size_t)i * NEXP;
    #pragma unroll
    for (int e = 0; e < NEXP; e++) acc[e] = fmaf(hv, wr[e], acc[e]);
  }
  #pragma unroll
  for (int mk = 1; mk < 64; mk <<= 1)
    #pragma unroll
    for (int e = 0; e < NEXP; e++) acc[e] += __shfl_xor(acc[e], mk);
  if (l == 0){
    float lg[NEXP], mx = -__builtin_inff();
    #pragma unroll
    for (int e = 0; e < NEXP; e++){ lg[e] = acc[e] + b3[e]; mx = fmaxf(mx, lg[e]); }
    float Z = 0.f, p[NEXP];
    #pragma unroll
    for (int e = 0; e < NEXP; e++){ p[e] = expf(lg[e] - mx); Z += p[e]; }
    float invZ = 1.0f / Z;
    #pragma unroll
    for (int e = 0; e < NEXP; e++) p[e] *= invZ;
    float gs[4];
    #pragma unroll
    for (int g = 0; g < 4; g++) gs[g] = fmaxf(p[2 * g], p[2 * g + 1]);
    int g1 = 0;
    #pragma unroll
    for (int g = 1; g < 4; g++) if (gs[g] > gs[g1]) g1 = g;
    int g2 = -1; float g2v = -__builtin_inff();
    #pragma unroll
    for (int g = 0; g < 4; g++) if (g != g1 && gs[g] > g2v){ g2v = gs[g]; g2 = g; }
    int best = 0; float bv = -__builtin_inff();
    #pragma unroll
    for (int e = 0; e < NEXP; e++){
      int g = e >> 1;
      if ((g == g1 || g == g2) && p[e] > bv){ bv = p[e]; best = e; }
    }
    out[t]         = bv;            // ROUTE_SCALE = 1.0
    out[T_TOK + t] = (float)best;   // idx as float
  }
}

// ---------------- driver ----------------
extern "C" void kernel_launch(void* const* d_in, const int* in_sizes, int n_in,
                              void* d_out, int out_size, void* d_ws, size_t ws_size,
                              hipStream_t stream){
  const float* x     = (const float*)d_in[0];
  const float* xproj = (const float*)d_in[1];
  const float* anw   = (const float*)d_in[2];
  const float* wq    = (const float*)d_in[3];
  const float* bq    = (const float*)d_in[4];
  const float* wk    = (const float*)d_in[5];
  const float* bk    = (const float*)d_in[6];
  const float* qnw   = (const float*)d_in[7];
  const float* knw   = (const float*)d_in[8];
  const float* w1    = (const float*)d_in[9];
  const float* b1    = (const float*)d_in[10];
  const float* w2    = (const float*)d_in[11];
  const float* b2    = (const float*)d_in[12];
  const float* w3    = (const float*)d_in[13];
  const float* b3    = (const float*)d_in[14];
  float* out = (float*)d_out;

  char* ws = (char*)d_ws;
  const size_t MB = 1024 * 1024;
  unsigned short* xn   = (unsigned short*)(ws);             // 8MB  [T][AHX] bf16
  unsigned short* wqkT = (unsigned short*)(ws + 8 * MB);    // 16MB [4096][2048] bf16
  float* QKf           = (float*)(ws + 24 * MB);            // 32MB [T][4096] f32 (dead after headnorm)
  unsigned short* Qnn  = (unsigned short*)(ws + 56 * MB);   // 8MB
  unsigned short* Knn  = (unsigned short*)(ws + 64 * MB);   // 8MB
  float* zpart         = (float*)(ws + 72 * MB);            // 1MB [8][16][2048]
  float* rc            = (float*)(ws + 73 * MB);            // 128KB
  float* imp_part      = (float*)(ws + 74 * MB);            // 2MB [256][2048]
  float* bqk           = (float*)(ws + 76 * MB);            // 16KB
  unsigned short* xh   = (unsigned short*)(ws + 77 * MB);   // 4MB
  unsigned short* xl   = (unsigned short*)(ws + 81 * MB);   // 4MB
  // overlap dead QKf region (valid after headnorm):
  unsigned short* w1Th = (unsigned short*)(ws + 24 * MB);   // 2MB each
  unsigned short* w1Tl = (unsigned short*)(ws + 26 * MB);
  unsigned short* w2Th = (unsigned short*)(ws + 28 * MB);
  unsigned short* w2Tl = (unsigned short*)(ws + 30 * MB);
  unsigned short* h1h  = (unsigned short*)(ws + 32 * MB);   // 4MB
  unsigned short* h1l  = (unsigned short*)(ws + 36 * MB);   // 4MB
  float* h2            = (float*)(ws + 40 * MB);            // 8MB

  dim3 tb(32, 8);
  k_split_cast<<<(T_TOK * DIMX) / 256, 256, 0, stream>>>(x, xh, xl, T_TOK * DIMX);
  k_rmsnorm_rows<<<T_TOK, 256, 0, stream>>>(xproj, anw, xn);
  k_transpose_cast<<<dim3(AHX / 32, AHX / 32), tb, 0, stream>>>(wq, wqkT, AHX, AHX);
  k_transpose_cast<<<dim3(AHX / 32, AHX / 32), tb, 0, stream>>>(wk, wqkT + (size_t)AHX * AHX, AHX, AHX);
  hipMemcpyAsync(bqk,        bq, AHX * sizeof(float), hipMemcpyDeviceToDevice, stream);
  hipMemcpyAsync(bqk + AHX,  bk, AHX * sizeof(float), hipMemcpyDeviceToDevice, stream);

  // fused Q|K projection: C [2048][4096]
  k_gemm_qk<<<dim3(32, 16), 256, 0, stream>>>(xn, wqkT, bqk, QKf, T_TOK, 2 * AHX, AHX);
  k_headnorm<<<T_TOK * NHEAD, 64, 0, stream>>>(QKf,        qnw, Qnn, 2 * AHX);
  k_headnorm<<<T_TOK * NHEAD, 64, 0, stream>>>(QKf + AHX,  knw, Knn, 2 * AHX);

  // QKf now dead -> MLP weight prep in its region
  k_transpose_cast_split<<<dim3(HIDX / 32, DIMX / 32), tb, 0, stream>>>(w1, w1Th, w1Tl, DIMX, HIDX);
  k_transpose_cast_split<<<dim3(HIDX / 32, HIDX / 32), tb, 0, stream>>>(w2, w2Th, w2Tl, HIDX, HIDX);

  // scores: denominators then per-tile importance partials
  k_z<<<dim3(16, NHEAD, 8), 256, 0, stream>>>(Qnn, Knn, zpart);
  k_rc<<<(NHEAD * T_TOK) / 256, 256, 0, stream>>>(zpart, rc);
  k_imp<<<dim3(16, NHEAD, 16), 256, 0, stream>>>(Qnn, Knn, rc, imp_part);
  k_impred<<<T_TOK / 256, 256, 0, stream>>>(imp_part, out + 2 * T_TOK);

  // router MLP (split-bf16 fp32 emulation) + routing
  k_gemm_bt<64, 1><<<dim3(HIDX / 128, T_TOK / 64), 256, 0, stream>>>(
      xh, xl, w1Th, w1Tl, b1, nullptr, h1h, h1l, T_TOK, HIDX, DIMX);
  k_gemm_bt<64, 2><<<dim3(HIDX / 128, T_TOK / 64), 256, 0, stream>>>(
      h1h, h1l, w2Th, w2Tl, b2, h2, nullptr, nullptr, T_TOK, HIDX, HIDX);
  k_router<<<T_TOK / 4, 256, 0, stream>>>(h2, w3, b3, out);

  (void)in_sizes; (void)n_in; (void)out_size; (void)ws_size;
}

// Round 4
// 250.587 us; speedup vs baseline: 1.8072x; 1.0933x over previous
//
#include <hip/hip_runtime.h>

#define T_TOK 2048
#define DIMX  1024
#define AHX   2048
#define HIDX  1024
#define NEXP  8
#define NHEAD 16
#define HD    128

typedef short bf16x8 __attribute__((ext_vector_type(8)));
typedef float f32x4  __attribute__((ext_vector_type(4)));

__device__ __forceinline__ unsigned short f2bf(float f){
  unsigned int u = __builtin_bit_cast(unsigned int, f);
  u += 0x7FFFu + ((u >> 16) & 1u);          // RNE
  return (unsigned short)(u >> 16);
}
__device__ __forceinline__ float bf2f(unsigned short h){
  unsigned int u = ((unsigned int)h) << 16;
  return __builtin_bit_cast(float, u);
}
__device__ __forceinline__ float gelu_exact(float x){
  return 0.5f * x * (1.0f + erff(x * 0.70710678118654752440f));
}
__device__ __forceinline__ void gload16(const unsigned short* g, unsigned short* l){
  __builtin_amdgcn_global_load_lds((const __attribute__((address_space(1))) unsigned int*)g,
                                   (__attribute__((address_space(3))) unsigned int*)l, 16, 0, 0);
}

// ---------------- transpose + cast: fp32 [R,C] -> bf16 [C,R] ----------------
__global__ void k_transpose_cast(const float* __restrict__ in,
                                 unsigned short* __restrict__ out, int R, int C){
  __shared__ float tile[32][33];
  int bx = blockIdx.x * 32, by = blockIdx.y * 32;
  int tx = threadIdx.x, ty = threadIdx.y;
  #pragma unroll
  for (int i = 0; i < 32; i += 8)
    tile[ty + i][tx] = in[(size_t)(by + ty + i) * C + bx + tx];
  __syncthreads();
  #pragma unroll
  for (int i = 0; i < 32; i += 8)
    out[(size_t)(bx + ty + i) * R + by + tx] = f2bf(tile[tx][ty + i]);
}

__global__ void k_transpose_cast_split(const float* __restrict__ in,
                                       unsigned short* __restrict__ outh,
                                       unsigned short* __restrict__ outl, int R, int C){
  __shared__ float tile[32][33];
  int bx = blockIdx.x * 32, by = blockIdx.y * 32;
  int tx = threadIdx.x, ty = threadIdx.y;
  #pragma unroll
  for (int i = 0; i < 32; i += 8)
    tile[ty + i][tx] = in[(size_t)(by + ty + i) * C + bx + tx];
  __syncthreads();
  #pragma unroll
  for (int i = 0; i < 32; i += 8){
    float v = tile[tx][ty + i];
    unsigned short h = f2bf(v);
    size_t o = (size_t)(bx + ty + i) * R + by + tx;
    outh[o] = h;
    outl[o] = f2bf(v - bf2f(h));
  }
}

__global__ void k_split_cast(const float* __restrict__ in,
                             unsigned short* __restrict__ hi,
                             unsigned short* __restrict__ lo, int n){
  int i = blockIdx.x * 256 + threadIdx.x;
  if (i >= n) return;
  float v = in[i];
  unsigned short h = f2bf(v);
  hi[i] = h;
  lo[i] = f2bf(v - bf2f(h));
}

// ---------------- rmsnorm over rows of [T, AHX], out bf16 ----------------
__global__ __launch_bounds__(256) void k_rmsnorm_rows(const float* __restrict__ in,
                                                      const float* __restrict__ w,
                                                      unsigned short* __restrict__ out){
  int row = blockIdx.x;
  const float* p = in + (size_t)row * AHX;
  int t = threadIdx.x;
  float v[8];
  *(float4*)&v[0] = *(const float4*)(p + t * 8);
  *(float4*)&v[4] = *(const float4*)(p + t * 8 + 4);
  float s = 0.f;
  #pragma unroll
  for (int i = 0; i < 8; i++) s += v[i] * v[i];
  #pragma unroll
  for (int m = 1; m < 64; m <<= 1) s += __shfl_xor(s, m);
  __shared__ float ps[4];
  if ((t & 63) == 0) ps[t >> 6] = s;
  __syncthreads();
  float tot = ps[0] + ps[1] + ps[2] + ps[3];
  float rs = rsqrtf(tot * (1.0f / AHX) + 1e-6f);
  #pragma unroll
  for (int i = 0; i < 8; i++)
    out[(size_t)row * AHX + t * 8 + i] = f2bf(v[i] * rs * w[t * 8 + i]);
}

// ------- fused Q|K projection GEMM + per-head rmsnorm epilogue -> bf16 -------
// C[M,4096] = A[M,K]*B[N,K]^T + bias; each 128-col tile == one head; rmsnorm
// over the tile's columns (2-wave LDS exchange) then *norm_w, cast bf16.
// BK=64, global_load_lds width 16, linear [128][64] LDS (m97 structure).
__global__ __launch_bounds__(256) void k_gemm_qk(
    const unsigned short* __restrict__ A, const unsigned short* __restrict__ B,
    const float* __restrict__ bq, const float* __restrict__ bk,
    const float* __restrict__ qnw, const float* __restrict__ knw,
    unsigned short* __restrict__ Qnn, unsigned short* __restrict__ Knn, int K)
{
  __shared__ __align__(16) unsigned short sA[128 * 64];
  __shared__ __align__(16) unsigned short sB[128 * 64];
  __shared__ float sums[128][2];
  int tid = threadIdx.x;
  int bm = blockIdx.y * 128;
  int bnB = blockIdx.x * 128;           // row into B [4096][K]
  int w = tid >> 6, l = tid & 63;
  int wm = (w >> 1) * 64, wn = (w & 1) * 64;
  int lhi = l >> 4, llo = l & 15;
  int rg = l >> 3, cg = (l & 7) * 8;    // gload lane row/col within 8x64 chunk

  f32x4 acc[4][4] = {};

  for (int k0 = 0; k0 < K; k0 += 64){
    __syncthreads();
    #pragma unroll
    for (int i = 0; i < 4; i++){
      int rb = w * 32 + i * 8;          // wave-uniform row base
      gload16(&A[(size_t)(bm + rb + rg) * K + k0 + cg], &sA[rb * 64]);
      gload16(&B[(size_t)(bnB + rb + rg) * K + k0 + cg], &sB[rb * 64]);
    }
    __syncthreads();
    bf16x8 af[2][4], bfr[2][4];
    #pragma unroll
    for (int kk = 0; kk < 2; kk++)
      #pragma unroll
      for (int m = 0; m < 4; m++){
        af[kk][m]  = *(const bf16x8*)&sA[(wm + m * 16 + llo) * 64 + kk * 32 + lhi * 8];
        bfr[kk][m] = *(const bf16x8*)&sB[(wn + m * 16 + llo) * 64 + kk * 32 + lhi * 8];
      }
    #pragma unroll
    for (int kk = 0; kk < 2; kk++)
      #pragma unroll
      for (int m = 0; m < 4; m++)
        #pragma unroll
        for (int n = 0; n < 4; n++)
          acc[m][n] = __builtin_amdgcn_mfma_f32_16x16x32_bf16(af[kk][m], bfr[kk][n], acc[m][n], 0, 0, 0);
  }

  bool isq = blockIdx.x < 16;
  const float* bias = isq ? bq : bk;
  const float* nw   = isq ? qnw : knw;
  unsigned short* outp = isq ? Qnn : Knn;
  int hcol0 = (blockIdx.x & 15) * 128;  // head base col within [T][2048]

  // bias add
  #pragma unroll
  for (int n = 0; n < 4; n++){
    float bv = bias[hcol0 + wn + n * 16 + llo];
    #pragma unroll
    for (int m = 0; m < 4; m++)
      #pragma unroll
      for (int j = 0; j < 4; j++) acc[m][n][j] += bv;
  }
  // per-row sum of squares over this wave's 64 cols
  #pragma unroll
  for (int m = 0; m < 4; m++)
    #pragma unroll
    for (int j = 0; j < 4; j++){
      float p = 0.f;
      #pragma unroll
      for (int n = 0; n < 4; n++) p += acc[m][n][j] * acc[m][n][j];
      p += __shfl_xor(p, 1); p += __shfl_xor(p, 2);
      p += __shfl_xor(p, 4); p += __shfl_xor(p, 8);
      if (llo == 0) sums[wm + m * 16 + lhi * 4 + j][w & 1] = p;
    }
  __syncthreads();
  #pragma unroll
  for (int m = 0; m < 4; m++)
    #pragma unroll
    for (int j = 0; j < 4; j++){
      int row = wm + m * 16 + lhi * 4 + j;
      float rs = rsqrtf((sums[row][0] + sums[row][1]) * (1.0f / HD) + 1e-6f);
      #pragma unroll
      for (int n = 0; n < 4; n++){
        int col = wn + n * 16 + llo;
        outp[(size_t)(bm + row) * AHX + hcol0 + col] = f2bf(acc[m][n][j] * rs * nw[col]);
      }
    }
}

// ---------------- MLP GEMM: C = A*B^T (+bias, epilogue), split-bf16 fp32 emulation ----------
template<int BM, int EPI>
__global__ __launch_bounds__(256) void k_gemm_bt(
    const unsigned short* __restrict__ Ah_, const unsigned short* __restrict__ Al_,
    const unsigned short* __restrict__ Bh_, const unsigned short* __restrict__ Bl_,
    const float* __restrict__ bias,
    float* __restrict__ Cf, unsigned short* __restrict__ Ch, unsigned short* __restrict__ Cl,
    int M, int N, int K)
{
  constexpr int LDT = 40;
  constexpr int MR = BM / 32;
  __shared__ __align__(16) unsigned short sA[BM * LDT];
  __shared__ __align__(16) unsigned short sB[128 * LDT];
  __shared__ __align__(16) unsigned short sAl[BM * LDT];
  __shared__ __align__(16) unsigned short sBl[128 * LDT];

  int tid = threadIdx.x;
  int bm = blockIdx.y * BM, bn = blockIdx.x * 128;
  int w = tid >> 6, l = tid & 63;
  int wm = (w >> 1) * (MR * 16), wn = (w & 1) * 64;
  int lhi = l >> 4, llo = l & 15;

  f32x4 acc[MR][4] = {};

  for (int k0 = 0; k0 < K; k0 += 32){
    __syncthreads();
    #pragma unroll
    for (int i = 0; i < BM / 64; i++){
      int chunk = tid + i * 256;
      int r = chunk >> 2, c = (chunk & 3) * 8;
      *(uint4*)&sA[r * LDT + c]  = *(const uint4*)&Ah_[(size_t)(bm + r) * K + k0 + c];
      *(uint4*)&sAl[r * LDT + c] = *(const uint4*)&Al_[(size_t)(bm + r) * K + k0 + c];
    }
    #pragma unroll
    for (int i = 0; i < 2; i++){
      int chunk = tid + i * 256;
      int r = chunk >> 2, c = (chunk & 3) * 8;
      *(uint4*)&sB[r * LDT + c]  = *(const uint4*)&Bh_[(size_t)(bn + r) * K + k0 + c];
      *(uint4*)&sBl[r * LDT + c] = *(const uint4*)&Bl_[(size_t)(bn + r) * K + k0 + c];
    }
    __syncthreads();
    bf16x8 af[MR], afl[MR], bfr[4], bfl[4];
    #pragma unroll
    for (int m = 0; m < MR; m++){
      af[m]  = *(const bf16x8*)&sA[(wm + m * 16 + llo) * LDT + lhi * 8];
      afl[m] = *(const bf16x8*)&sAl[(wm + m * 16 + llo) * LDT + lhi * 8];
    }
    #pragma unroll
    for (int n = 0; n < 4; n++){
      bfr[n] = *(const bf16x8*)&sB[(wn + n * 16 + llo) * LDT + lhi * 8];
      bfl[n] = *(const bf16x8*)&sBl[(wn + n * 16 + llo) * LDT + lhi * 8];
    }
    #pragma unroll
    for (int m = 0; m < MR; m++)
      #pragma unroll
      for (int n = 0; n < 4; n++){
        acc[m][n] = __builtin_amdgcn_mfma_f32_16x16x32_bf16(af[m],  bfr[n], acc[m][n], 0, 0, 0);
        acc[m][n] = __builtin_amdgcn_mfma_f32_16x16x32_bf16(af[m],  bfl[n], acc[m][n], 0, 0, 0);
        acc[m][n] = __builtin_amdgcn_mfma_f32_16x16x32_bf16(afl[m], bfr[n], acc[m][n], 0, 0, 0);
      }
  }
  #pragma unroll
  for (int m = 0; m < MR; m++)
    #pragma unroll
    for (int n = 0; n < 4; n++){
      int col = bn + wn + n * 16 + llo;
      float bv = bias[col];
      #pragma unroll
      for (int j = 0; j < 4; j++){
        int row = bm + wm + m * 16 + lhi * 4 + j;
        float v = acc[m][n][j] + bv;
        size_t off = (size_t)row * N + col;
        if constexpr (EPI == 1){
          float g = gelu_exact(v);
          unsigned short hh = f2bf(g);
          Ch[off] = hh;
          Cl[off] = f2bf(g - bf2f(hh));
        } else {
          Cf[off] = gelu_exact(v);
        }
      }
    }
}

// ---------------- scores denominator: zpart[ks][h][row] = sum_k exp(s) over K-chunk --------
__global__ __launch_bounds__(256) void k_z(const unsigned short* __restrict__ Qn,
                                           const unsigned short* __restrict__ Kn,
                                           float* __restrict__ zpart){
  __shared__ __align__(16) unsigned short sK[128 * 128];
  int h = blockIdx.y;
  int qb = blockIdx.x * 128;
  int tid = threadIdx.x, w = tid >> 6, l = tid & 63;
  int lhi = l >> 4, llo = l & 15;
  int wq = qb + w * 32;
  const float scale = 0.08838834764831845f;

  bf16x8 qf[2][4];
  #pragma unroll
  for (int m = 0; m < 2; m++)
    #pragma unroll
    for (int kk = 0; kk < 4; kk++)
      qf[m][kk] = *(const bf16x8*)&Qn[(size_t)(wq + m * 16 + llo) * AHX + h * HD + kk * 32 + lhi * 8];

  float rz[2][4] = {};

  for (int t = 0; t < 2; t++){
    int kt = blockIdx.z * 256 + t * 128;
    __syncthreads();
    #pragma unroll
    for (int i = 0; i < 8; i++){
      int chunk = tid + i * 256;
      int r = chunk >> 4, c = (chunk & 15) * 8;
      *(uint4*)&sK[r * 128 + (c ^ ((r & 7) << 3))] =
          *(const uint4*)&Kn[(size_t)(kt + r) * AHX + h * HD + c];
    }
    __syncthreads();
    f32x4 acc[2][8] = {};
    #pragma unroll
    for (int n = 0; n < 8; n++){
      int row = n * 16 + llo;
      #pragma unroll
      for (int kk = 0; kk < 4; kk++){
        bf16x8 kf = *(const bf16x8*)&sK[row * 128 + ((kk * 32 + lhi * 8) ^ ((llo & 7) << 3))];
        acc[0][n] = __builtin_amdgcn_mfma_f32_16x16x32_bf16(qf[0][kk], kf, acc[0][n], 0, 0, 0);
        acc[1][n] = __builtin_amdgcn_mfma_f32_16x16x32_bf16(qf[1][kk], kf, acc[1][n], 0, 0, 0);
      }
    }
    #pragma unroll
    for (int m = 0; m < 2; m++)
      #pragma unroll
      for (int j = 0; j < 4; j++){
        float s = 0.f;
        #pragma unroll
        for (int n = 0; n < 8; n++) s += __expf(acc[m][n][j] * scale);
        rz[m][j] += s;
      }
  }
  #pragma unroll
  for (int m = 0; m < 2; m++)
    #pragma unroll
    for (int j = 0; j < 4; j++){
      float s = rz[m][j];
      s += __shfl_xor(s, 1); s += __shfl_xor(s, 2);
      s += __shfl_xor(s, 4); s += __shfl_xor(s, 8);
      if (llo == 0){
        int row = wq + m * 16 + lhi * 4 + j;
        zpart[(size_t)blockIdx.z * (NHEAD * T_TOK) + h * T_TOK + row] = s;
      }
    }
}

// ---------------- rc[h][row] = 1/(NHEAD * Z) ----------------
__global__ void k_rc(const float* __restrict__ zpart, float* __restrict__ rc){
  int i = blockIdx.x * 256 + threadIdx.x;   // NHEAD*T_TOK = 32768
  float s = 0.f;
  #pragma unroll
  for (int p = 0; p < 8; p++) s += zpart[p * (NHEAD * T_TOK) + i];
  rc[i] = 1.0f / ((float)NHEAD * s);
}

// ---------------- importance partials: one 128x128 tile per block ----------------
__global__ __launch_bounds__(256) void k_imp(const unsigned short* __restrict__ Qn,
                                             const unsigned short* __restrict__ Kn,
                                             const float* __restrict__ rc,
                                             float* __restrict__ imp_part){
  __shared__ __align__(16) unsigned short sK[128 * 128];
  __shared__ float simp[4][128];
  int h = blockIdx.y;
  int qb = blockIdx.x * 128;
  int kt = blockIdx.z * 128;
  int tid = threadIdx.x, w = tid >> 6, l = tid & 63;
  int lhi = l >> 4, llo = l & 15;
  int wq = qb + w * 32;
  const float scale = 0.08838834764831845f;

  bf16x8 qf[2][4];
  float rcv[2][4];
  #pragma unroll
  for (int m = 0; m < 2; m++)
    #pragma unroll
    for (int kk = 0; kk < 4; kk++)
      qf[m][kk] = *(const bf16x8*)&Qn[(size_t)(wq + m * 16 + llo) * AHX + h * HD + kk * 32 + lhi * 8];
  #pragma unroll
  for (int m = 0; m < 2; m++)
    #pragma unroll
    for (int j = 0; j < 4; j++)
      rcv[m][j] = rc[h * T_TOK + wq + m * 16 + lhi * 4 + j];

  #pragma unroll
  for (int i = 0; i < 8; i++){
    int chunk = tid + i * 256;
    int r = chunk >> 4, c = (chunk & 15) * 8;
    *(uint4*)&sK[r * 128 + (c ^ ((r & 7) << 3))] =
        *(const uint4*)&Kn[(size_t)(kt + r) * AHX + h * HD + c];
  }
  __syncthreads();
  f32x4 acc[2][8] = {};
  #pragma unroll
  for (int n = 0; n < 8; n++){
    int row = n * 16 + llo;
    #pragma unroll
    for (int kk = 0; kk < 4; kk++){
      bf16x8 kf = *(const bf16x8*)&sK[row * 128 + ((kk * 32 + lhi * 8) ^ ((llo & 7) << 3))];
      acc[0][n] = __builtin_amdgcn_mfma_f32_16x16x32_bf16(qf[0][kk], kf, acc[0][n], 0, 0, 0);
      acc[1][n] = __builtin_amdgcn_mfma_f32_16x16x32_bf16(qf[1][kk], kf, acc[1][n], 0, 0, 0);
    }
  }
  #pragma unroll
  for (int n = 0; n < 8; n++){
    float s = 0.f;
    #pragma unroll
    for (int m = 0; m < 2; m++)
      #pragma unroll
      for (int j = 0; j < 4; j++)
        s += __expf(acc[m][n][j] * scale) * rcv[m][j];
    s += __shfl_xor(s, 16);
    s += __shfl_xor(s, 32);
    if (l < 16) simp[w][n * 16 + l] = s;
  }
  __syncthreads();
  if (tid < 128){
    float tot = simp[0][tid] + simp[1][tid] + simp[2][tid] + simp[3][tid];
    imp_part[((size_t)blockIdx.x * NHEAD + h) * T_TOK + kt + tid] = tot;
  }
}

// ---------------- importance reduction over 256 partial rows ----------------
__global__ void k_impred(const float* __restrict__ imp_part, float* __restrict__ imp){
  int col = blockIdx.x * 256 + threadIdx.x;
  float s = 0.f;
  for (int r = 0; r < 256; r++) s += imp_part[(size_t)r * T_TOK + col];
  imp[col] = s;
}

// ---------------- router: logits, softmax, grouped top-k ----------------
__global__ __launch_bounds__(256) void k_router(const float* __restrict__ h2,
                                                const float* __restrict__ w3,
                                                const float* __restrict__ b3,
                                                float* __restrict__ out){
  int t = blockIdx.x * 4 + (threadIdx.x >> 6);
  int l = threadIdx.x & 63;
  const float* hp = h2 + (size_t)t * HIDX;
  float acc[NEXP] = {};
  for (int i = l; i < HIDX; i += 64){
    float hv = hp[i];
    const float* wr = w3 + (size_t)i * NEXP;
    #pragma unroll
    for (int e = 0; e < NEXP; e++) acc[e] = fmaf(hv, wr[e], acc[e]);
  }
  #pragma unroll
  for (int mk = 1; mk < 64; mk <<= 1)
    #pragma unroll
    for (int e = 0; e < NEXP; e++) acc[e] += __shfl_xor(acc[e], mk);
  if (l == 0){
    float lg[NEXP], mx = -__builtin_inff();
    #pragma unroll
    for (int e = 0; e < NEXP; e++){ lg[e] = acc[e] + b3[e]; mx = fmaxf(mx, lg[e]); }
    float Z = 0.f, p[NEXP];
    #pragma unroll
    for (int e = 0; e < NEXP; e++){ p[e] = expf(lg[e] - mx); Z += p[e]; }
    float invZ = 1.0f / Z;
    #pragma unroll
    for (int e = 0; e < NEXP; e++) p[e] *= invZ;
    float gs[4];
    #pragma unroll
    for (int g = 0; g < 4; g++) gs[g] = fmaxf(p[2 * g], p[2 * g + 1]);
    int g1 = 0;
    #pragma unroll
    for (int g = 1; g < 4; g++) if (gs[g] > gs[g1]) g1 = g;
    int g2 = -1; float g2v = -__builtin_inff();
    #pragma unroll
    for (int g = 0; g < 4; g++) if (g != g1 && gs[g] > g2v){ g2v = gs[g]; g2 = g; }
    int best = 0; float bv = -__builtin_inff();
    #pragma unroll
    for (int e = 0; e < NEXP; e++){
      int g = e >> 1;
      if ((g == g1 || g == g2) && p[e] > bv){ bv = p[e]; best = e; }
    }
    out[t]         = bv;            // ROUTE_SCALE = 1.0
    out[T_TOK + t] = (float)best;   // idx as float
  }
}

// ---------------- driver ----------------
extern "C" void kernel_launch(void* const* d_in, const int* in_sizes, int n_in,
                              void* d_out, int out_size, void* d_ws, size_t ws_size,
                              hipStream_t stream){
  const float* x     = (const float*)d_in[0];
  const float* xproj = (const float*)d_in[1];
  const float* anw   = (const float*)d_in[2];
  const float* wq    = (const float*)d_in[3];
  const float* bq    = (const float*)d_in[4];
  const float* wk    = (const float*)d_in[5];
  const float* bk    = (const float*)d_in[6];
  const float* qnw   = (const float*)d_in[7];
  const float* knw   = (const float*)d_in[8];
  const float* w1    = (const float*)d_in[9];
  const float* b1    = (const float*)d_in[10];
  const float* w2    = (const float*)d_in[11];
  const float* b2    = (const float*)d_in[12];
  const float* w3    = (const float*)d_in[13];
  const float* b3    = (const float*)d_in[14];
  float* out = (float*)d_out;

  char* ws = (char*)d_ws;
  const size_t MB = 1024 * 1024;
  unsigned short* xn   = (unsigned short*)(ws);             // 8MB  [T][AHX] bf16
  unsigned short* wqkT = (unsigned short*)(ws + 8 * MB);    // 16MB [4096][2048] bf16
  unsigned short* Qnn  = (unsigned short*)(ws + 24 * MB);   // 8MB
  unsigned short* Knn  = (unsigned short*)(ws + 32 * MB);   // 8MB
  float* zpart         = (float*)(ws + 40 * MB);            // 1MB [8][16][2048]
  float* rc            = (float*)(ws + 41 * MB);            // 128KB
  float* imp_part      = (float*)(ws + 42 * MB);            // 2MB [256][2048]
  unsigned short* xh   = (unsigned short*)(ws + 44 * MB);   // 4MB
  unsigned short* xl   = (unsigned short*)(ws + 48 * MB);   // 4MB
  unsigned short* w1Th = (unsigned short*)(ws + 52 * MB);   // 2MB each
  unsigned short* w1Tl = (unsigned short*)(ws + 54 * MB);
  unsigned short* w2Th = (unsigned short*)(ws + 56 * MB);
  unsigned short* w2Tl = (unsigned short*)(ws + 58 * MB);
  unsigned short* h1h  = (unsigned short*)(ws + 60 * MB);   // 4MB
  unsigned short* h1l  = (unsigned short*)(ws + 64 * MB);   // 4MB
  float* h2            = (float*)(ws + 68 * MB);            // 8MB

  dim3 tb(32, 8);
  k_split_cast<<<(T_TOK * DIMX) / 256, 256, 0, stream>>>(x, xh, xl, T_TOK * DIMX);
  k_rmsnorm_rows<<<T_TOK, 256, 0, stream>>>(xproj, anw, xn);
  k_transpose_cast<<<dim3(AHX / 32, AHX / 32), tb, 0, stream>>>(wq, wqkT, AHX, AHX);
  k_transpose_cast<<<dim3(AHX / 32, AHX / 32), tb, 0, stream>>>(wk, wqkT + (size_t)AHX * AHX, AHX, AHX);

  // fused Q|K projection + per-head rmsnorm -> Qnn/Knn bf16
  k_gemm_qk<<<dim3(32, 16), 256, 0, stream>>>(xn, wqkT, bq, bk, qnw, knw, Qnn, Knn, AHX);

  // MLP weight prep
  k_transpose_cast_split<<<dim3(HIDX / 32, DIMX / 32), tb, 0, stream>>>(w1, w1Th, w1Tl, DIMX, HIDX);
  k_transpose_cast_split<<<dim3(HIDX / 32, HIDX / 32), tb, 0, stream>>>(w2, w2Th, w2Tl, HIDX, HIDX);

  // scores: denominators then per-tile importance partials
  k_z<<<dim3(16, NHEAD, 8), 256, 0, stream>>>(Qnn, Knn, zpart);
  k_rc<<<(NHEAD * T_TOK) / 256, 256, 0, stream>>>(zpart, rc);
  k_imp<<<dim3(16, NHEAD, 16), 256, 0, stream>>>(Qnn, Knn, rc, imp_part);
  k_impred<<<T_TOK / 256, 256, 0, stream>>>(imp_part, out + 2 * T_TOK);

  // router MLP (split-bf16 fp32 emulation) + routing
  k_gemm_bt<64, 1><<<dim3(HIDX / 128, T_TOK / 64), 256, 0, stream>>>(
      xh, xl, w1Th, w1Tl, b1, nullptr, h1h, h1l, T_TOK, HIDX, DIMX);
  k_gemm_bt<64, 2><<<dim3(HIDX / 128, T_TOK / 64), 256, 0, stream>>>(
      h1h, h1l, w2Th, w2Tl, b2, h2, nullptr, nullptr, T_TOK, HIDX, HIDX);
  k_router<<<T_TOK / 4, 256, 0, stream>>>(h2, w3, b3, out);

  (void)in_sizes; (void)n_in; (void)out_size; (void)ws_size;
}

// Round 5
// 207.147 us; speedup vs baseline: 2.1862x; 1.2097x over previous
//
#include <hip/hip_runtime.h>

#define T_TOK 2048
#define DIMX  1024
#define AHX   2048
#define HIDX  1024
#define NEXP  8
#define NHEAD 16
#define HD    128

typedef short bf16x8 __attribute__((ext_vector_type(8)));
typedef float f32x4  __attribute__((ext_vector_type(4)));

__device__ __forceinline__ unsigned short f2bf(float f){
  unsigned int u = __builtin_bit_cast(unsigned int, f);
  u += 0x7FFFu + ((u >> 16) & 1u);          // RNE
  return (unsigned short)(u >> 16);
}
__device__ __forceinline__ float bf2f(unsigned short h){
  unsigned int u = ((unsigned int)h) << 16;
  return __builtin_bit_cast(float, u);
}
__device__ __forceinline__ float gelu_exact(float x){
  return 0.5f * x * (1.0f + erff(x * 0.70710678118654752440f));
}
__device__ __forceinline__ void gload16(const unsigned short* g, unsigned short* l){
  __builtin_amdgcn_global_load_lds((const __attribute__((address_space(1))) unsigned int*)g,
                                   (__attribute__((address_space(3))) unsigned int*)l, 16, 0, 0);
}

// ---------------- transpose + cast: fp32 [R,C] -> bf16 [C,R] ----------------
__global__ void k_transpose_cast(const float* __restrict__ in,
                                 unsigned short* __restrict__ out, int R, int C){
  __shared__ float tile[32][33];
  int bx = blockIdx.x * 32, by = blockIdx.y * 32;
  int tx = threadIdx.x, ty = threadIdx.y;
  #pragma unroll
  for (int i = 0; i < 32; i += 8)
    tile[ty + i][tx] = in[(size_t)(by + ty + i) * C + bx + tx];
  __syncthreads();
  #pragma unroll
  for (int i = 0; i < 32; i += 8)
    out[(size_t)(bx + ty + i) * R + by + tx] = f2bf(tile[tx][ty + i]);
}

__global__ void k_transpose_cast_split(const float* __restrict__ in,
                                       unsigned short* __restrict__ outh,
                                       unsigned short* __restrict__ outl, int R, int C){
  __shared__ float tile[32][33];
  int bx = blockIdx.x * 32, by = blockIdx.y * 32;
  int tx = threadIdx.x, ty = threadIdx.y;
  #pragma unroll
  for (int i = 0; i < 32; i += 8)
    tile[ty + i][tx] = in[(size_t)(by + ty + i) * C + bx + tx];
  __syncthreads();
  #pragma unroll
  for (int i = 0; i < 32; i += 8){
    float v = tile[tx][ty + i];
    unsigned short h = f2bf(v);
    size_t o = (size_t)(bx + ty + i) * R + by + tx;
    outh[o] = h;
    outl[o] = f2bf(v - bf2f(h));
  }
}

__global__ void k_split_cast(const float* __restrict__ in,
                             unsigned short* __restrict__ hi,
                             unsigned short* __restrict__ lo, int n){
  int i = blockIdx.x * 256 + threadIdx.x;
  if (i >= n) return;
  float v = in[i];
  unsigned short h = f2bf(v);
  hi[i] = h;
  lo[i] = f2bf(v - bf2f(h));
}

// ---------------- rmsnorm over rows of [T, AHX], out bf16 ----------------
__global__ __launch_bounds__(256) void k_rmsnorm_rows(const float* __restrict__ in,
                                                      const float* __restrict__ w,
                                                      unsigned short* __restrict__ out){
  int row = blockIdx.x;
  const float* p = in + (size_t)row * AHX;
  int t = threadIdx.x;
  float v[8];
  *(float4*)&v[0] = *(const float4*)(p + t * 8);
  *(float4*)&v[4] = *(const float4*)(p + t * 8 + 4);
  float s = 0.f;
  #pragma unroll
  for (int i = 0; i < 8; i++) s += v[i] * v[i];
  #pragma unroll
  for (int m = 1; m < 64; m <<= 1) s += __shfl_xor(s, m);
  __shared__ float ps[4];
  if ((t & 63) == 0) ps[t >> 6] = s;
  __syncthreads();
  float tot = ps[0] + ps[1] + ps[2] + ps[3];
  float rs = rsqrtf(tot * (1.0f / AHX) + 1e-6f);
  #pragma unroll
  for (int i = 0; i < 8; i++)
    out[(size_t)row * AHX + t * 8 + i] = f2bf(v[i] * rs * w[t * 8 + i]);
}

// ------- fused Q|K projection GEMM + per-head rmsnorm epilogue -> bf16 -------
// BK=64, double-buffered LDS, gload_lds with inverse-swizzled SOURCE +
// swizzled READ (chunk ^= row&7) -> conflict-free ds_read_b128.
__global__ __launch_bounds__(256) void k_gemm_qk(
    const unsigned short* __restrict__ A, const unsigned short* __restrict__ B,
    const float* __restrict__ bq, const float* __restrict__ bk,
    const float* __restrict__ qnw, const float* __restrict__ knw,
    unsigned short* __restrict__ Qnn, unsigned short* __restrict__ Knn, int K)
{
  __shared__ __align__(16) unsigned short sA[2][128 * 64];
  __shared__ __align__(16) unsigned short sB[2][128 * 64];
  __shared__ float sums[128][2];
  int tid = threadIdx.x;
  int bm = blockIdx.y * 128;
  int bnB = blockIdx.x * 128;
  int w = tid >> 6, l = tid & 63;
  int wm = (w >> 1) * 64, wn = (w & 1) * 64;
  int lhi = l >> 4, llo = l & 15;
  int srow = l >> 3;                    // row within 8-row staging group
  int scol = ((l & 7) ^ srow) * 8;      // inverse-swizzled source chunk
  int swz = llo & 7;                    // read-side XOR (row&7)

  const unsigned short* pA = &A[(size_t)(bm + w * 32 + srow) * K + scol];
  const unsigned short* pB = &B[(size_t)(bnB + w * 32 + srow) * K + scol];

  f32x4 acc[4][4] = {};

  // prologue: stage tile 0 into buf 0
  #pragma unroll
  for (int i = 0; i < 4; i++){
    gload16(pA + (size_t)i * 8 * K, &sA[0][(w * 32 + i * 8) * 64]);
    gload16(pB + (size_t)i * 8 * K, &sB[0][(w * 32 + i * 8) * 64]);
  }
  __syncthreads();

  int cur = 0;
  for (int k0 = 0; k0 < K; k0 += 64){
    if (k0 + 64 < K){
      #pragma unroll
      for (int i = 0; i < 4; i++){
        gload16(pA + (size_t)i * 8 * K + k0 + 64, &sA[cur ^ 1][(w * 32 + i * 8) * 64]);
        gload16(pB + (size_t)i * 8 * K + k0 + 64, &sB[cur ^ 1][(w * 32 + i * 8) * 64]);
      }
    }
    bf16x8 af[2][4], bfr[2][4];
    #pragma unroll
    for (int kk = 0; kk < 2; kk++){
      int ca = ((kk * 4 + lhi) ^ swz) * 8;
      #pragma unroll
      for (int m = 0; m < 4; m++){
        af[kk][m]  = *(const bf16x8*)&sA[cur][(wm + m * 16 + llo) * 64 + ca];
        bfr[kk][m] = *(const bf16x8*)&sB[cur][(wn + m * 16 + llo) * 64 + ca];
      }
    }
    #pragma unroll
    for (int kk = 0; kk < 2; kk++)
      #pragma unroll
      for (int m = 0; m < 4; m++)
        #pragma unroll
        for (int n = 0; n < 4; n++)
          acc[m][n] = __builtin_amdgcn_mfma_f32_16x16x32_bf16(af[kk][m], bfr[kk][n], acc[m][n], 0, 0, 0);
    __syncthreads();
    cur ^= 1;
  }

  bool isq = blockIdx.x < 16;
  const float* bias = isq ? bq : bk;
  const float* nw   = isq ? qnw : knw;
  unsigned short* outp = isq ? Qnn : Knn;
  int hcol0 = (blockIdx.x & 15) * 128;

  #pragma unroll
  for (int n = 0; n < 4; n++){
    float bv = bias[hcol0 + wn + n * 16 + llo];
    #pragma unroll
    for (int m = 0; m < 4; m++)
      #pragma unroll
      for (int j = 0; j < 4; j++) acc[m][n][j] += bv;
  }
  #pragma unroll
  for (int m = 0; m < 4; m++)
    #pragma unroll
    for (int j = 0; j < 4; j++){
      float p = 0.f;
      #pragma unroll
      for (int n = 0; n < 4; n++) p += acc[m][n][j] * acc[m][n][j];
      p += __shfl_xor(p, 1); p += __shfl_xor(p, 2);
      p += __shfl_xor(p, 4); p += __shfl_xor(p, 8);
      if (llo == 0) sums[wm + m * 16 + lhi * 4 + j][w & 1] = p;
    }
  __syncthreads();
  #pragma unroll
  for (int m = 0; m < 4; m++)
    #pragma unroll
    for (int j = 0; j < 4; j++){
      int row = wm + m * 16 + lhi * 4 + j;
      float rs = rsqrtf((sums[row][0] + sums[row][1]) * (1.0f / HD) + 1e-6f);
      #pragma unroll
      for (int n = 0; n < 4; n++){
        int col = wn + n * 16 + llo;
        outp[(size_t)(bm + row) * AHX + hcol0 + col] = f2bf(acc[m][n][j] * rs * nw[col]);
      }
    }
}

// -------- MLP GEMM: C[M,N] = A*B^T (+bias, epilogue), split-bf16 fp32 emulation ---------
// BM=64, BN=64, BK=64; dbuf gload_lds, swizzled source/read.
// EPI 1: gelu -> bf16 hi/lo. EPI 2: gelu -> fp32.
template<int EPI>
__global__ __launch_bounds__(256) void k_gemm_mlp(
    const unsigned short* __restrict__ Ah_, const unsigned short* __restrict__ Al_,
    const unsigned short* __restrict__ Bh_, const unsigned short* __restrict__ Bl_,
    const float* __restrict__ bias,
    float* __restrict__ Cf, unsigned short* __restrict__ Ch, unsigned short* __restrict__ Cl,
    int N, int K)
{
  __shared__ __align__(16) unsigned short sAh[2][64 * 64], sAl[2][64 * 64];
  __shared__ __align__(16) unsigned short sBh[2][64 * 64], sBl[2][64 * 64];
  int tid = threadIdx.x;
  int bm = blockIdx.y * 64, bn = blockIdx.x * 64;
  int w = tid >> 6, l = tid & 63;
  int wm = (w >> 1) * 32, wn = (w & 1) * 32;
  int lhi = l >> 4, llo = l & 15;
  int srow = l >> 3;
  int scol = ((l & 7) ^ srow) * 8;
  int swz = llo & 7;

  const unsigned short* pAh = &Ah_[(size_t)(bm + w * 8 + srow) * K + scol];
  const unsigned short* pAl = &Al_[(size_t)(bm + w * 8 + srow) * K + scol];
  const unsigned short* pBh = &Bh_[(size_t)(bn + w * 8 + srow) * K + scol];
  const unsigned short* pBl = &Bl_[(size_t)(bn + w * 8 + srow) * K + scol];

  f32x4 acc[2][2] = {};

  auto stage = [&](int buf, int k0){
    #pragma unroll
    for (int i = 0; i < 2; i++){
      int rb = (i * 32 + w * 8) * 64;
      gload16(pAh + (size_t)i * 32 * K + k0, &sAh[buf][rb]);
      gload16(pAl + (size_t)i * 32 * K + k0, &sAl[buf][rb]);
      gload16(pBh + (size_t)i * 32 * K + k0, &sBh[buf][rb]);
      gload16(pBl + (size_t)i * 32 * K + k0, &sBl[buf][rb]);
    }
  };

  stage(0, 0);
  __syncthreads();

  int cur = 0;
  for (int k0 = 0; k0 < K; k0 += 64){
    if (k0 + 64 < K) stage(cur ^ 1, k0 + 64);
    bf16x8 ah[2][2], al[2][2], bh[2][2], bl[2][2];
    #pragma unroll
    for (int kk = 0; kk < 2; kk++){
      int ca = ((kk * 4 + lhi) ^ swz) * 8;
      #pragma unroll
      for (int m = 0; m < 2; m++){
        ah[kk][m] = *(const bf16x8*)&sAh[cur][(wm + m * 16 + llo) * 64 + ca];
        al[kk][m] = *(const bf16x8*)&sAl[cur][(wm + m * 16 + llo) * 64 + ca];
        bh[kk][m] = *(const bf16x8*)&sBh[cur][(wn + m * 16 + llo) * 64 + ca];
        bl[kk][m] = *(const bf16x8*)&sBl[cur][(wn + m * 16 + llo) * 64 + ca];
      }
    }
    #pragma unroll
    for (int kk = 0; kk < 2; kk++)
      #pragma unroll
      for (int m = 0; m < 2; m++)
        #pragma unroll
        for (int n = 0; n < 2; n++){
          acc[m][n] = __builtin_amdgcn_mfma_f32_16x16x32_bf16(ah[kk][m], bh[kk][n], acc[m][n], 0, 0, 0);
          acc[m][n] = __builtin_amdgcn_mfma_f32_16x16x32_bf16(ah[kk][m], bl[kk][n], acc[m][n], 0, 0, 0);
          acc[m][n] = __builtin_amdgcn_mfma_f32_16x16x32_bf16(al[kk][m], bh[kk][n], acc[m][n], 0, 0, 0);
        }
    __syncthreads();
    cur ^= 1;
  }

  #pragma unroll
  for (int m = 0; m < 2; m++)
    #pragma unroll
    for (int n = 0; n < 2; n++){
      int col = bn + wn + n * 16 + llo;
      float bv = bias[col];
      #pragma unroll
      for (int j = 0; j < 4; j++){
        int row = bm + wm + m * 16 + lhi * 4 + j;
        float v = acc[m][n][j] + bv;
        size_t off = (size_t)row * N + col;
        if constexpr (EPI == 1){
          float g = gelu_exact(v);
          unsigned short hh = f2bf(g);
          Ch[off] = hh;
          Cl[off] = f2bf(g - bf2f(hh));
        } else {
          Cf[off] = gelu_exact(v);
        }
      }
    }
}

// ---------------- scores denominator: zpart[ks][h][row] = sum_k exp(s) over K-chunk --------
__global__ __launch_bounds__(256) void k_z(const unsigned short* __restrict__ Qn,
                                           const unsigned short* __restrict__ Kn,
                                           float* __restrict__ zpart){
  __shared__ __align__(16) unsigned short sK[128 * 128];
  int h = blockIdx.y;
  int qb = blockIdx.x * 128;
  int tid = threadIdx.x, w = tid >> 6, l = tid & 63;
  int lhi = l >> 4, llo = l & 15;
  int wq = qb + w * 32;
  const float scale = 0.08838834764831845f;

  bf16x8 qf[2][4];
  #pragma unroll
  for (int m = 0; m < 2; m++)
    #pragma unroll
    for (int kk = 0; kk < 4; kk++)
      qf[m][kk] = *(const bf16x8*)&Qn[(size_t)(wq + m * 16 + llo) * AHX + h * HD + kk * 32 + lhi * 8];

  float rz[2][4] = {};

  for (int t = 0; t < 2; t++){
    int kt = blockIdx.z * 256 + t * 128;
    __syncthreads();
    #pragma unroll
    for (int i = 0; i < 8; i++){
      int chunk = tid + i * 256;
      int r = chunk >> 4, c = (chunk & 15) * 8;
      *(uint4*)&sK[r * 128 + (c ^ ((r & 7) << 3))] =
          *(const uint4*)&Kn[(size_t)(kt + r) * AHX + h * HD + c];
    }
    __syncthreads();
    f32x4 acc[2][8] = {};
    #pragma unroll
    for (int n = 0; n < 8; n++){
      int row = n * 16 + llo;
      #pragma unroll
      for (int kk = 0; kk < 4; kk++){
        bf16x8 kf = *(const bf16x8*)&sK[row * 128 + ((kk * 32 + lhi * 8) ^ ((llo & 7) << 3))];
        acc[0][n] = __builtin_amdgcn_mfma_f32_16x16x32_bf16(qf[0][kk], kf, acc[0][n], 0, 0, 0);
        acc[1][n] = __builtin_amdgcn_mfma_f32_16x16x32_bf16(qf[1][kk], kf, acc[1][n], 0, 0, 0);
      }
    }
    #pragma unroll
    for (int m = 0; m < 2; m++)
      #pragma unroll
      for (int j = 0; j < 4; j++){
        float s = 0.f;
        #pragma unroll
        for (int n = 0; n < 8; n++) s += __expf(acc[m][n][j] * scale);
        rz[m][j] += s;
      }
  }
  #pragma unroll
  for (int m = 0; m < 2; m++)
    #pragma unroll
    for (int j = 0; j < 4; j++){
      float s = rz[m][j];
      s += __shfl_xor(s, 1); s += __shfl_xor(s, 2);
      s += __shfl_xor(s, 4); s += __shfl_xor(s, 8);
      if (llo == 0){
        int row = wq + m * 16 + lhi * 4 + j;
        zpart[(size_t)blockIdx.z * (NHEAD * T_TOK) + h * T_TOK + row] = s;
      }
    }
}

// ---------------- rc[h][row] = 1/(NHEAD * Z) ----------------
__global__ void k_rc(const float* __restrict__ zpart, float* __restrict__ rc){
  int i = blockIdx.x * 256 + threadIdx.x;   // NHEAD*T_TOK = 32768
  float s = 0.f;
  #pragma unroll
  for (int p = 0; p < 8; p++) s += zpart[p * (NHEAD * T_TOK) + i];
  rc[i] = 1.0f / ((float)NHEAD * s);
}

// ---------------- importance partials: one 128x128 tile per block ----------------
__global__ __launch_bounds__(256) void k_imp(const unsigned short* __restrict__ Qn,
                                             const unsigned short* __restrict__ Kn,
                                             const float* __restrict__ rc,
                                             float* __restrict__ imp_part){
  __shared__ __align__(16) unsigned short sK[128 * 128];
  __shared__ float simp[4][128];
  int h = blockIdx.y;
  int qb = blockIdx.x * 128;
  int kt = blockIdx.z * 128;
  int tid = threadIdx.x, w = tid >> 6, l = tid & 63;
  int lhi = l >> 4, llo = l & 15;
  int wq = qb + w * 32;
  const float scale = 0.08838834764831845f;

  bf16x8 qf[2][4];
  float rcv[2][4];
  #pragma unroll
  for (int m = 0; m < 2; m++)
    #pragma unroll
    for (int kk = 0; kk < 4; kk++)
      qf[m][kk] = *(const bf16x8*)&Qn[(size_t)(wq + m * 16 + llo) * AHX + h * HD + kk * 32 + lhi * 8];
  #pragma unroll
  for (int m = 0; m < 2; m++)
    #pragma unroll
    for (int j = 0; j < 4; j++)
      rcv[m][j] = rc[h * T_TOK + wq + m * 16 + lhi * 4 + j];

  #pragma unroll
  for (int i = 0; i < 8; i++){
    int chunk = tid + i * 256;
    int r = chunk >> 4, c = (chunk & 15) * 8;
    *(uint4*)&sK[r * 128 + (c ^ ((r & 7) << 3))] =
        *(const uint4*)&Kn[(size_t)(kt + r) * AHX + h * HD + c];
  }
  __syncthreads();
  f32x4 acc[2][8] = {};
  #pragma unroll
  for (int n = 0; n < 8; n++){
    int row = n * 16 + llo;
    #pragma unroll
    for (int kk = 0; kk < 4; kk++){
      bf16x8 kf = *(const bf16x8*)&sK[row * 128 + ((kk * 32 + lhi * 8) ^ ((llo & 7) << 3))];
      acc[0][n] = __builtin_amdgcn_mfma_f32_16x16x32_bf16(qf[0][kk], kf, acc[0][n], 0, 0, 0);
      acc[1][n] = __builtin_amdgcn_mfma_f32_16x16x32_bf16(qf[1][kk], kf, acc[1][n], 0, 0, 0);
    }
  }
  #pragma unroll
  for (int n = 0; n < 8; n++){
    float s = 0.f;
    #pragma unroll
    for (int m = 0; m < 2; m++)
      #pragma unroll
      for (int j = 0; j < 4; j++)
        s += __expf(acc[m][n][j] * scale) * rcv[m][j];
    s += __shfl_xor(s, 16);
    s += __shfl_xor(s, 32);
    if (l < 16) simp[w][n * 16 + l] = s;
  }
  __syncthreads();
  if (tid < 128){
    float tot = simp[0][tid] + simp[1][tid] + simp[2][tid] + simp[3][tid];
    imp_part[((size_t)blockIdx.x * NHEAD + h) * T_TOK + kt + tid] = tot;
  }
}

// ---------------- importance reduction over 256 partial rows ----------------
__global__ void k_impred(const float* __restrict__ imp_part, float* __restrict__ imp){
  int col = blockIdx.x * 256 + threadIdx.x;
  float s = 0.f;
  for (int r = 0; r < 256; r++) s += imp_part[(size_t)r * T_TOK + col];
  imp[col] = s;
}

// ---------------- router: logits, softmax, grouped top-k ----------------
__global__ __launch_bounds__(256) void k_router(const float* __restrict__ h2,
                                                const float* __restrict__ w3,
                                                const float* __restrict__ b3,
                                                float* __restrict__ out){
  int t = blockIdx.x * 4 + (threadIdx.x >> 6);
  int l = threadIdx.x & 63;
  const float* hp = h2 + (size_t)t * HIDX;
  float acc[NEXP] = {};
  for (int i = l; i < HIDX; i += 64){
    float hv = hp[i];
    const float* wr = w3 + (size_t)i * NEXP;
    #pragma unroll
    for (int e = 0; e < NEXP; e++) acc[e] = fmaf(hv, wr[e], acc[e]);
  }
  #pragma unroll
  for (int mk = 1; mk < 64; mk <<= 1)
    #pragma unroll
    for (int e = 0; e < NEXP; e++) acc[e] += __shfl_xor(acc[e], mk);
  if (l == 0){
    float lg[NEXP], mx = -__builtin_inff();
    #pragma unroll
    for (int e = 0; e < NEXP; e++){ lg[e] = acc[e] + b3[e]; mx = fmaxf(mx, lg[e]); }
    float Z = 0.f, p[NEXP];
    #pragma unroll
    for (int e = 0; e < NEXP; e++){ p[e] = expf(lg[e] - mx); Z += p[e]; }
    float invZ = 1.0f / Z;
    #pragma unroll
    for (int e = 0; e < NEXP; e++) p[e] *= invZ;
    float gs[4];
    #pragma unroll
    for (int g = 0; g < 4; g++) gs[g] = fmaxf(p[2 * g], p[2 * g + 1]);
    int g1 = 0;
    #pragma unroll
    for (int g = 1; g < 4; g++) if (gs[g] > gs[g1]) g1 = g;
    int g2 = -1; float g2v = -__builtin_inff();
    #pragma unroll
    for (int g = 0; g < 4; g++) if (g != g1 && gs[g] > g2v){ g2v = gs[g]; g2 = g; }
    int best = 0; float bv = -__builtin_inff();
    #pragma unroll
    for (int e = 0; e < NEXP; e++){
      int g = e >> 1;
      if ((g == g1 || g == g2) && p[e] > bv){ bv = p[e]; best = e; }
    }
    out[t]         = bv;            // ROUTE_SCALE = 1.0
    out[T_TOK + t] = (float)best;   // idx as float
  }
}

// ---------------- driver ----------------
extern "C" void kernel_launch(void* const* d_in, const int* in_sizes, int n_in,
                              void* d_out, int out_size, void* d_ws, size_t ws_size,
                              hipStream_t stream){
  const float* x     = (const float*)d_in[0];
  const float* xproj = (const float*)d_in[1];
  const float* anw   = (const float*)d_in[2];
  const float* wq    = (const float*)d_in[3];
  const float* bq    = (const float*)d_in[4];
  const float* wk    = (const float*)d_in[5];
  const float* bk    = (const float*)d_in[6];
  const float* qnw   = (const float*)d_in[7];
  const float* knw   = (const float*)d_in[8];
  const float* w1    = (const float*)d_in[9];
  const float* b1    = (const float*)d_in[10];
  const float* w2    = (const float*)d_in[11];
  const float* b2    = (const float*)d_in[12];
  const float* w3    = (const float*)d_in[13];
  const float* b3    = (const float*)d_in[14];
  float* out = (float*)d_out;

  char* ws = (char*)d_ws;
  const size_t MB = 1024 * 1024;
  unsigned short* xn   = (unsigned short*)(ws);             // 8MB  [T][AHX] bf16
  unsigned short* wqkT = (unsigned short*)(ws + 8 * MB);    // 16MB [4096][2048] bf16
  unsigned short* Qnn  = (unsigned short*)(ws + 24 * MB);   // 8MB
  unsigned short* Knn  = (unsigned short*)(ws + 32 * MB);   // 8MB
  float* zpart         = (float*)(ws + 40 * MB);            // 1MB [8][16][2048]
  float* rc            = (float*)(ws + 41 * MB);            // 128KB
  float* imp_part      = (float*)(ws + 42 * MB);            // 2MB [256][2048]
  unsigned short* xh   = (unsigned short*)(ws + 44 * MB);   // 4MB
  unsigned short* xl   = (unsigned short*)(ws + 48 * MB);   // 4MB
  unsigned short* w1Th = (unsigned short*)(ws + 52 * MB);   // 2MB each
  unsigned short* w1Tl = (unsigned short*)(ws + 54 * MB);
  unsigned short* w2Th = (unsigned short*)(ws + 56 * MB);
  unsigned short* w2Tl = (unsigned short*)(ws + 58 * MB);
  unsigned short* h1h  = (unsigned short*)(ws + 60 * MB);   // 4MB
  unsigned short* h1l  = (unsigned short*)(ws + 64 * MB);   // 4MB
  float* h2            = (float*)(ws + 68 * MB);            // 8MB

  dim3 tb(32, 8);
  k_split_cast<<<(T_TOK * DIMX) / 256, 256, 0, stream>>>(x, xh, xl, T_TOK * DIMX);
  k_rmsnorm_rows<<<T_TOK, 256, 0, stream>>>(xproj, anw, xn);
  k_transpose_cast<<<dim3(AHX / 32, AHX / 32), tb, 0, stream>>>(wq, wqkT, AHX, AHX);
  k_transpose_cast<<<dim3(AHX / 32, AHX / 32), tb, 0, stream>>>(wk, wqkT + (size_t)AHX * AHX, AHX, AHX);

  // fused Q|K projection + per-head rmsnorm -> Qnn/Knn bf16
  k_gemm_qk<<<dim3(32, 16), 256, 0, stream>>>(xn, wqkT, bq, bk, qnw, knw, Qnn, Knn, AHX);

  // MLP weight prep
  k_transpose_cast_split<<<dim3(HIDX / 32, DIMX / 32), tb, 0, stream>>>(w1, w1Th, w1Tl, DIMX, HIDX);
  k_transpose_cast_split<<<dim3(HIDX / 32, HIDX / 32), tb, 0, stream>>>(w2, w2Th, w2Tl, HIDX, HIDX);

  // scores: denominators then per-tile importance partials
  k_z<<<dim3(16, NHEAD, 8), 256, 0, stream>>>(Qnn, Knn, zpart);
  k_rc<<<(NHEAD * T_TOK) / 256, 256, 0, stream>>>(zpart, rc);
  k_imp<<<dim3(16, NHEAD, 16), 256, 0, stream>>>(Qnn, Knn, rc, imp_part);
  k_impred<<<T_TOK / 256, 256, 0, stream>>>(imp_part, out + 2 * T_TOK);

  // router MLP (split-bf16 fp32 emulation) + routing
  k_gemm_mlp<1><<<dim3(HIDX / 64, T_TOK / 64), 256, 0, stream>>>(
      xh, xl, w1Th, w1Tl, b1, nullptr, h1h, h1l, HIDX, DIMX);
  k_gemm_mlp<2><<<dim3(HIDX / 64, T_TOK / 64), 256, 0, stream>>>(
      h1h, h1l, w2Th, w2Tl, b2, h2, nullptr, nullptr, HIDX, HIDX);
  k_router<<<T_TOK / 4, 256, 0, stream>>>(h2, w3, b3, out);

  (void)in_sizes; (void)n_in; (void)out_size; (void)ws_size;
}

// Round 6
// 194.508 us; speedup vs baseline: 2.3282x; 1.0650x over previous
//
#include <hip/hip_runtime.h>

#define T_TOK 2048
#define DIMX  1024
#define AHX   2048
#define HIDX  1024
#define NEXP  8
#define NHEAD 16
#define HD    128

typedef short bf16x8 __attribute__((ext_vector_type(8)));
typedef float f32x4  __attribute__((ext_vector_type(4)));

__device__ __forceinline__ unsigned short f2bf(float f){
  unsigned int u = __builtin_bit_cast(unsigned int, f);
  u += 0x7FFFu + ((u >> 16) & 1u);          // RNE
  return (unsigned short)(u >> 16);
}
__device__ __forceinline__ float bf2f(unsigned short h){
  unsigned int u = ((unsigned int)h) << 16;
  return __builtin_bit_cast(float, u);
}
__device__ __forceinline__ float gelu_exact(float x){
  return 0.5f * x * (1.0f + erff(x * 0.70710678118654752440f));
}
__device__ __forceinline__ void gload16(const unsigned short* g, unsigned short* l){
  __builtin_amdgcn_global_load_lds((const __attribute__((address_space(1))) unsigned int*)g,
                                   (__attribute__((address_space(3))) unsigned int*)l, 16, 0, 0);
}

// ------------- prep: split_cast(x) [blocks 0..8191] + rmsnorm(xproj) [8192..10239] -------------
__global__ __launch_bounds__(256) void k_prep(const float* __restrict__ x,
                                              unsigned short* __restrict__ xh,
                                              unsigned short* __restrict__ xl,
                                              const float* __restrict__ xproj,
                                              const float* __restrict__ anw,
                                              unsigned short* __restrict__ xn){
  int bx = blockIdx.x, t = threadIdx.x;
  if (bx < 8192){
    int i = bx * 256 + t;
    float v = x[i];
    unsigned short h = f2bf(v);
    xh[i] = h;
    xl[i] = f2bf(v - bf2f(h));
    return;
  }
  int row = bx - 8192;
  const float* p = xproj + (size_t)row * AHX;
  float v[8];
  *(float4*)&v[0] = *(const float4*)(p + t * 8);
  *(float4*)&v[4] = *(const float4*)(p + t * 8 + 4);
  float s = 0.f;
  #pragma unroll
  for (int i = 0; i < 8; i++) s += v[i] * v[i];
  #pragma unroll
  for (int m = 1; m < 64; m <<= 1) s += __shfl_xor(s, m);
  __shared__ float ps[4];
  if ((t & 63) == 0) ps[t >> 6] = s;
  __syncthreads();
  float tot = ps[0] + ps[1] + ps[2] + ps[3];
  float rs = rsqrtf(tot * (1.0f / AHX) + 1e-6f);
  #pragma unroll
  for (int i = 0; i < 8; i++)
    xn[(size_t)row * AHX + t * 8 + i] = f2bf(v[i] * rs * anw[t * 8 + i]);
}

// ---------------- transpose+cast wq|wk (z selects) -> bf16 [C,R] ----------------
__global__ void k_transpose_qk(const float* __restrict__ wq, const float* __restrict__ wk,
                               unsigned short* __restrict__ out){
  const float* in = blockIdx.z ? wk : wq;
  unsigned short* o = out + (size_t)blockIdx.z * AHX * AHX;
  __shared__ float tile[32][33];
  int bx = blockIdx.x * 32, by = blockIdx.y * 32;
  int tx = threadIdx.x, ty = threadIdx.y;
  #pragma unroll
  for (int i = 0; i < 32; i += 8)
    tile[ty + i][tx] = in[(size_t)(by + ty + i) * AHX + bx + tx];
  __syncthreads();
  #pragma unroll
  for (int i = 0; i < 32; i += 8)
    o[(size_t)(bx + ty + i) * AHX + by + tx] = f2bf(tile[tx][ty + i]);
}

// ---------------- transpose+split w1|w2 (z selects), 1024x1024 ----------------
__global__ void k_transpose_w12(const float* __restrict__ w1, const float* __restrict__ w2,
                                unsigned short* __restrict__ w1h, unsigned short* __restrict__ w1l,
                                unsigned short* __restrict__ w2h, unsigned short* __restrict__ w2l){
  const float* in = blockIdx.z ? w2 : w1;
  unsigned short* oh = blockIdx.z ? w2h : w1h;
  unsigned short* ol = blockIdx.z ? w2l : w1l;
  __shared__ float tile[32][33];
  int bx = blockIdx.x * 32, by = blockIdx.y * 32;
  int tx = threadIdx.x, ty = threadIdx.y;
  #pragma unroll
  for (int i = 0; i < 32; i += 8)
    tile[ty + i][tx] = in[(size_t)(by + ty + i) * HIDX + bx + tx];
  __syncthreads();
  #pragma unroll
  for (int i = 0; i < 32; i += 8){
    float v = tile[tx][ty + i];
    unsigned short h = f2bf(v);
    size_t o = (size_t)(bx + ty + i) * DIMX + by + tx;
    oh[o] = h;
    ol[o] = f2bf(v - bf2f(h));
  }
}

// ------- fused Q|K projection GEMM + per-head rmsnorm epilogue -> bf16 -------
__global__ __launch_bounds__(256) void k_gemm_qk(
    const unsigned short* __restrict__ A, const unsigned short* __restrict__ B,
    const float* __restrict__ bq, const float* __restrict__ bk,
    const float* __restrict__ qnw, const float* __restrict__ knw,
    unsigned short* __restrict__ Qnn, unsigned short* __restrict__ Knn, int K)
{
  __shared__ __align__(16) unsigned short sA[2][128 * 64];
  __shared__ __align__(16) unsigned short sB[2][128 * 64];
  __shared__ float sums[128][2];
  int tid = threadIdx.x;
  int bm = blockIdx.y * 128;
  int bnB = blockIdx.x * 128;
  int w = tid >> 6, l = tid & 63;
  int wm = (w >> 1) * 64, wn = (w & 1) * 64;
  int lhi = l >> 4, llo = l & 15;
  int srow = l >> 3;
  int scol = ((l & 7) ^ srow) * 8;
  int swz = llo & 7;

  const unsigned short* pA = &A[(size_t)(bm + w * 32 + srow) * K + scol];
  const unsigned short* pB = &B[(size_t)(bnB + w * 32 + srow) * K + scol];

  f32x4 acc[4][4] = {};

  #pragma unroll
  for (int i = 0; i < 4; i++){
    gload16(pA + (size_t)i * 8 * K, &sA[0][(w * 32 + i * 8) * 64]);
    gload16(pB + (size_t)i * 8 * K, &sB[0][(w * 32 + i * 8) * 64]);
  }
  __syncthreads();

  int cur = 0;
  for (int k0 = 0; k0 < K; k0 += 64){
    if (k0 + 64 < K){
      #pragma unroll
      for (int i = 0; i < 4; i++){
        gload16(pA + (size_t)i * 8 * K + k0 + 64, &sA[cur ^ 1][(w * 32 + i * 8) * 64]);
        gload16(pB + (size_t)i * 8 * K + k0 + 64, &sB[cur ^ 1][(w * 32 + i * 8) * 64]);
      }
    }
    bf16x8 af[2][4], bfr[2][4];
    #pragma unroll
    for (int kk = 0; kk < 2; kk++){
      int ca = ((kk * 4 + lhi) ^ swz) * 8;
      #pragma unroll
      for (int m = 0; m < 4; m++){
        af[kk][m]  = *(const bf16x8*)&sA[cur][(wm + m * 16 + llo) * 64 + ca];
        bfr[kk][m] = *(const bf16x8*)&sB[cur][(wn + m * 16 + llo) * 64 + ca];
      }
    }
    #pragma unroll
    for (int kk = 0; kk < 2; kk++)
      #pragma unroll
      for (int m = 0; m < 4; m++)
        #pragma unroll
        for (int n = 0; n < 4; n++)
          acc[m][n] = __builtin_amdgcn_mfma_f32_16x16x32_bf16(af[kk][m], bfr[kk][n], acc[m][n], 0, 0, 0);
    __syncthreads();
    cur ^= 1;
  }

  bool isq = blockIdx.x < 16;
  const float* bias = isq ? bq : bk;
  const float* nw   = isq ? qnw : knw;
  unsigned short* outp = isq ? Qnn : Knn;
  int hcol0 = (blockIdx.x & 15) * 128;

  #pragma unroll
  for (int n = 0; n < 4; n++){
    float bv = bias[hcol0 + wn + n * 16 + llo];
    #pragma unroll
    for (int m = 0; m < 4; m++)
      #pragma unroll
      for (int j = 0; j < 4; j++) acc[m][n][j] += bv;
  }
  #pragma unroll
  for (int m = 0; m < 4; m++)
    #pragma unroll
    for (int j = 0; j < 4; j++){
      float p = 0.f;
      #pragma unroll
      for (int n = 0; n < 4; n++) p += acc[m][n][j] * acc[m][n][j];
      p += __shfl_xor(p, 1); p += __shfl_xor(p, 2);
      p += __shfl_xor(p, 4); p += __shfl_xor(p, 8);
      if (llo == 0) sums[wm + m * 16 + lhi * 4 + j][w & 1] = p;
    }
  __syncthreads();
  #pragma unroll
  for (int m = 0; m < 4; m++)
    #pragma unroll
    for (int j = 0; j < 4; j++){
      int row = wm + m * 16 + lhi * 4 + j;
      float rs = rsqrtf((sums[row][0] + sums[row][1]) * (1.0f / HD) + 1e-6f);
      #pragma unroll
      for (int n = 0; n < 4; n++){
        int col = wn + n * 16 + llo;
        outp[(size_t)(bm + row) * AHX + hcol0 + col] = f2bf(acc[m][n][j] * rs * nw[col]);
      }
    }
}

// -------- MLP GEMM: C[M,N] = A*B^T (+bias, epilogue), split-bf16 fp32 emulation ---------
template<int EPI>
__global__ __launch_bounds__(256) void k_gemm_mlp(
    const unsigned short* __restrict__ Ah_, const unsigned short* __restrict__ Al_,
    const unsigned short* __restrict__ Bh_, const unsigned short* __restrict__ Bl_,
    const float* __restrict__ bias,
    float* __restrict__ Cf, unsigned short* __restrict__ Ch, unsigned short* __restrict__ Cl,
    int N, int K)
{
  __shared__ __align__(16) unsigned short sAh[2][64 * 64], sAl[2][64 * 64];
  __shared__ __align__(16) unsigned short sBh[2][64 * 64], sBl[2][64 * 64];
  int tid = threadIdx.x;
  int bm = blockIdx.y * 64, bn = blockIdx.x * 64;
  int w = tid >> 6, l = tid & 63;
  int wm = (w >> 1) * 32, wn = (w & 1) * 32;
  int lhi = l >> 4, llo = l & 15;
  int srow = l >> 3;
  int scol = ((l & 7) ^ srow) * 8;
  int swz = llo & 7;

  const unsigned short* pAh = &Ah_[(size_t)(bm + w * 8 + srow) * K + scol];
  const unsigned short* pAl = &Al_[(size_t)(bm + w * 8 + srow) * K + scol];
  const unsigned short* pBh = &Bh_[(size_t)(bn + w * 8 + srow) * K + scol];
  const unsigned short* pBl = &Bl_[(size_t)(bn + w * 8 + srow) * K + scol];

  f32x4 acc[2][2] = {};

  auto stage = [&](int buf, int k0){
    #pragma unroll
    for (int i = 0; i < 2; i++){
      int rb = (i * 32 + w * 8) * 64;
      gload16(pAh + (size_t)i * 32 * K + k0, &sAh[buf][rb]);
      gload16(pAl + (size_t)i * 32 * K + k0, &sAl[buf][rb]);
      gload16(pBh + (size_t)i * 32 * K + k0, &sBh[buf][rb]);
      gload16(pBl + (size_t)i * 32 * K + k0, &sBl[buf][rb]);
    }
  };

  stage(0, 0);
  __syncthreads();

  int cur = 0;
  for (int k0 = 0; k0 < K; k0 += 64){
    if (k0 + 64 < K) stage(cur ^ 1, k0 + 64);
    bf16x8 ah[2][2], al[2][2], bh[2][2], bl[2][2];
    #pragma unroll
    for (int kk = 0; kk < 2; kk++){
      int ca = ((kk * 4 + lhi) ^ swz) * 8;
      #pragma unroll
      for (int m = 0; m < 2; m++){
        ah[kk][m] = *(const bf16x8*)&sAh[cur][(wm + m * 16 + llo) * 64 + ca];
        al[kk][m] = *(const bf16x8*)&sAl[cur][(wm + m * 16 + llo) * 64 + ca];
        bh[kk][m] = *(const bf16x8*)&sBh[cur][(wn + m * 16 + llo) * 64 + ca];
        bl[kk][m] = *(const bf16x8*)&sBl[cur][(wn + m * 16 + llo) * 64 + ca];
      }
    }
    #pragma unroll
    for (int kk = 0; kk < 2; kk++)
      #pragma unroll
      for (int m = 0; m < 2; m++)
        #pragma unroll
        for (int n = 0; n < 2; n++){
          acc[m][n] = __builtin_amdgcn_mfma_f32_16x16x32_bf16(ah[kk][m], bh[kk][n], acc[m][n], 0, 0, 0);
          acc[m][n] = __builtin_amdgcn_mfma_f32_16x16x32_bf16(ah[kk][m], bl[kk][n], acc[m][n], 0, 0, 0);
          acc[m][n] = __builtin_amdgcn_mfma_f32_16x16x32_bf16(al[kk][m], bh[kk][n], acc[m][n], 0, 0, 0);
        }
    __syncthreads();
    cur ^= 1;
  }

  #pragma unroll
  for (int m = 0; m < 2; m++)
    #pragma unroll
    for (int n = 0; n < 2; n++){
      int col = bn + wn + n * 16 + llo;
      float bv = bias[col];
      #pragma unroll
      for (int j = 0; j < 4; j++){
        int row = bm + wm + m * 16 + lhi * 4 + j;
        float v = acc[m][n][j] + bv;
        size_t off = (size_t)row * N + col;
        if constexpr (EPI == 1){
          float g = gelu_exact(v);
          unsigned short hh = f2bf(g);
          Ch[off] = hh;
          Cl[off] = f2bf(g - bf2f(hh));
        } else {
          Cf[off] = gelu_exact(v);
        }
      }
    }
}

// ---------------- scores denominator: zpart[ks][h][row], gload_lds + dbuf ----------------
__global__ __launch_bounds__(256) void k_z(const unsigned short* __restrict__ Qn,
                                           const unsigned short* __restrict__ Kn,
                                           float* __restrict__ zpart){
  __shared__ __align__(16) unsigned short sK[2][128 * 128];
  int h = blockIdx.y;
  int qb = blockIdx.x * 128;
  int tid = threadIdx.x, w = tid >> 6, l = tid & 63;
  int lhi = l >> 4, llo = l & 15;
  int wq = qb + w * 32;
  const float scale = 0.08838834764831845f;

  auto stageK = [&](int buf, int kt){
    #pragma unroll
    for (int i = 0; i < 8; i++){
      int rb = i * 16 + w * 4;
      int r = rb + (l >> 4);
      int c = ((l & 15) * 8) ^ ((r & 7) << 3);
      gload16(&Kn[(size_t)(kt + r) * AHX + h * HD + c], &sK[buf][rb * 128]);
    }
  };

  bf16x8 qf[2][4];
  #pragma unroll
  for (int m = 0; m < 2; m++)
    #pragma unroll
    for (int kk = 0; kk < 4; kk++)
      qf[m][kk] = *(const bf16x8*)&Qn[(size_t)(wq + m * 16 + llo) * AHX + h * HD + kk * 32 + lhi * 8];

  float rz[2][4] = {};
  int kt0 = blockIdx.z * 256;

  stageK(0, kt0);
  __syncthreads();

  #pragma unroll
  for (int t = 0; t < 2; t++){
    if (t == 0) stageK(1, kt0 + 128);
    f32x4 acc[2][8] = {};
    #pragma unroll
    for (int n = 0; n < 8; n++){
      int row = n * 16 + llo;
      #pragma unroll
      for (int kk = 0; kk < 4; kk++){
        bf16x8 kf = *(const bf16x8*)&sK[t][row * 128 + ((kk * 32 + lhi * 8) ^ ((llo & 7) << 3))];
        acc[0][n] = __builtin_amdgcn_mfma_f32_16x16x32_bf16(qf[0][kk], kf, acc[0][n], 0, 0, 0);
        acc[1][n] = __builtin_amdgcn_mfma_f32_16x16x32_bf16(qf[1][kk], kf, acc[1][n], 0, 0, 0);
      }
    }
    #pragma unroll
    for (int m = 0; m < 2; m++)
      #pragma unroll
      for (int j = 0; j < 4; j++){
        float s = 0.f;
        #pragma unroll
        for (int n = 0; n < 8; n++) s += __expf(acc[m][n][j] * scale);
        rz[m][j] += s;
      }
    if (t == 0) __syncthreads();
  }
  #pragma unroll
  for (int m = 0; m < 2; m++)
    #pragma unroll
    for (int j = 0; j < 4; j++){
      float s = rz[m][j];
      s += __shfl_xor(s, 1); s += __shfl_xor(s, 2);
      s += __shfl_xor(s, 4); s += __shfl_xor(s, 8);
      if (llo == 0){
        int row = wq + m * 16 + lhi * 4 + j;
        zpart[(size_t)blockIdx.z * (NHEAD * T_TOK) + h * T_TOK + row] = s;
      }
    }
}

// ---------------- rc[h][row] = 1/(NHEAD * Z) ----------------
__global__ void k_rc(const float* __restrict__ zpart, float* __restrict__ rc){
  int i = blockIdx.x * 256 + threadIdx.x;
  float s = 0.f;
  #pragma unroll
  for (int p = 0; p < 8; p++) s += zpart[p * (NHEAD * T_TOK) + i];
  rc[i] = 1.0f / ((float)NHEAD * s);
}

// ---------------- importance partials: 2 tiles per block, gload_lds + dbuf ----------------
__global__ __launch_bounds__(256) void k_imp(const unsigned short* __restrict__ Qn,
                                             const unsigned short* __restrict__ Kn,
                                             const float* __restrict__ rc,
                                             float* __restrict__ imp_part){
  __shared__ __align__(16) unsigned short sK[2][128 * 128];
  __shared__ float simp[4][128];
  int h = blockIdx.y;
  int qb = blockIdx.x * 128;
  int kt0 = blockIdx.z * 256;
  int tid = threadIdx.x, w = tid >> 6, l = tid & 63;
  int lhi = l >> 4, llo = l & 15;
  int wq = qb + w * 32;
  const float scale = 0.08838834764831845f;

  auto stageK = [&](int buf, int kt){
    #pragma unroll
    for (int i = 0; i < 8; i++){
      int rb = i * 16 + w * 4;
      int r = rb + (l >> 4);
      int c = ((l & 15) * 8) ^ ((r & 7) << 3);
      gload16(&Kn[(size_t)(kt + r) * AHX + h * HD + c], &sK[buf][rb * 128]);
    }
  };

  bf16x8 qf[2][4];
  float rcv[2][4];
  #pragma unroll
  for (int m = 0; m < 2; m++)
    #pragma unroll
    for (int kk = 0; kk < 4; kk++)
      qf[m][kk] = *(const bf16x8*)&Qn[(size_t)(wq + m * 16 + llo) * AHX + h * HD + kk * 32 + lhi * 8];
  #pragma unroll
  for (int m = 0; m < 2; m++)
    #pragma unroll
    for (int j = 0; j < 4; j++)
      rcv[m][j] = rc[h * T_TOK + wq + m * 16 + lhi * 4 + j];

  stageK(0, kt0);
  __syncthreads();

  #pragma unroll
  for (int t = 0; t < 2; t++){
    if (t == 0) stageK(1, kt0 + 128);
    f32x4 acc[2][8] = {};
    #pragma unroll
    for (int n = 0; n < 8; n++){
      int row = n * 16 + llo;
      #pragma unroll
      for (int kk = 0; kk < 4; kk++){
        bf16x8 kf = *(const bf16x8*)&sK[t][row * 128 + ((kk * 32 + lhi * 8) ^ ((llo & 7) << 3))];
        acc[0][n] = __builtin_amdgcn_mfma_f32_16x16x32_bf16(qf[0][kk], kf, acc[0][n], 0, 0, 0);
        acc[1][n] = __builtin_amdgcn_mfma_f32_16x16x32_bf16(qf[1][kk], kf, acc[1][n], 0, 0, 0);
      }
    }
    #pragma unroll
    for (int n = 0; n < 8; n++){
      float s = 0.f;
      #pragma unroll
      for (int m = 0; m < 2; m++)
        #pragma unroll
        for (int j = 0; j < 4; j++)
          s += __expf(acc[m][j / 4 * 0 + n][j] * 0.f + acc[m][n][j] * scale) * 0.f + __expf(acc[m][n][j] * scale) * rcv[m][j];
      s += __shfl_xor(s, 16);
      s += __shfl_xor(s, 32);
      if (l < 16) simp[w][n * 16 + l] = s;
    }
    __syncthreads();
    if (tid < 128){
      float tot = simp[0][tid] + simp[1][tid] + simp[2][tid] + simp[3][tid];
      imp_part[((size_t)blockIdx.x * NHEAD + h) * T_TOK + kt0 + t * 128 + tid] = tot;
    }
    if (t == 0) __syncthreads();
  }
}

// ---------------- final: impred [blocks 0..7] + router [8..519] ----------------
__global__ __launch_bounds__(256) void k_final(const float* __restrict__ imp_part,
                                               const float* __restrict__ h2,
                                               const float* __restrict__ w3,
                                               const float* __restrict__ b3,
                                               float* __restrict__ out){
  if (blockIdx.x < 8){
    int col = blockIdx.x * 256 + threadIdx.x;
    float s = 0.f;
    for (int r = 0; r < 256; r++) s += imp_part[(size_t)r * T_TOK + col];
    out[2 * T_TOK + col] = s;
    return;
  }
  int t = (blockIdx.x - 8) * 4 + (threadIdx.x >> 6);
  int l = threadIdx.x & 63;
  const float* hp = h2 + (size_t)t * HIDX;
  float acc[NEXP] = {};
  for (int i = l; i < HIDX; i += 64){
    float hv = hp[i];
    const float* wr = w3 + (size_t)i * NEXP;
    #pragma unroll
    for (int e = 0; e < NEXP; e++) acc[e] = fmaf(hv, wr[e], acc[e]);
  }
  #pragma unroll
  for (int mk = 1; mk < 64; mk <<= 1)
    #pragma unroll
    for (int e = 0; e < NEXP; e++) acc[e] += __shfl_xor(acc[e], mk);
  if (l == 0){
    float lg[NEXP], mx = -__builtin_inff();
    #pragma unroll
    for (int e = 0; e < NEXP; e++){ lg[e] = acc[e] + b3[e]; mx = fmaxf(mx, lg[e]); }
    float Z = 0.f, p[NEXP];
    #pragma unroll
    for (int e = 0; e < NEXP; e++){ p[e] = expf(lg[e] - mx); Z += p[e]; }
    float invZ = 1.0f / Z;
    #pragma unroll
    for (int e = 0; e < NEXP; e++) p[e] *= invZ;
    float gs[4];
    #pragma unroll
    for (int g = 0; g < 4; g++) gs[g] = fmaxf(p[2 * g], p[2 * g + 1]);
    int g1 = 0;
    #pragma unroll
    for (int g = 1; g < 4; g++) if (gs[g] > gs[g1]) g1 = g;
    int g2 = -1; float g2v = -__builtin_inff();
    #pragma unroll
    for (int g = 0; g < 4; g++) if (g != g1 && gs[g] > g2v){ g2v = gs[g]; g2 = g; }
    int best = 0; float bv = -__builtin_inff();
    #pragma unroll
    for (int e = 0; e < NEXP; e++){
      int g = e >> 1;
      if ((g == g1 || g == g2) && p[e] > bv){ bv = p[e]; best = e; }
    }
    out[t]         = bv;            // ROUTE_SCALE = 1.0
    out[T_TOK + t] = (float)best;   // idx as float
  }
}

// ---------------- driver ----------------
extern "C" void kernel_launch(void* const* d_in, const int* in_sizes, int n_in,
                              void* d_out, int out_size, void* d_ws, size_t ws_size,
                              hipStream_t stream){
  const float* x     = (const float*)d_in[0];
  const float* xproj = (const float*)d_in[1];
  const float* anw   = (const float*)d_in[2];
  const float* wq    = (const float*)d_in[3];
  const float* bq    = (const float*)d_in[4];
  const float* wk    = (const float*)d_in[5];
  const float* bk    = (const float*)d_in[6];
  const float* qnw   = (const float*)d_in[7];
  const float* knw   = (const float*)d_in[8];
  const float* w1    = (const float*)d_in[9];
  const float* b1    = (const float*)d_in[10];
  const float* w2    = (const float*)d_in[11];
  const float* b2    = (const float*)d_in[12];
  const float* w3    = (const float*)d_in[13];
  const float* b3    = (const float*)d_in[14];
  float* out = (float*)d_out;

  char* ws = (char*)d_ws;
  const size_t MB = 1024 * 1024;
  unsigned short* xn   = (unsigned short*)(ws);             // 8MB  [T][AHX] bf16
  unsigned short* wqkT = (unsigned short*)(ws + 8 * MB);    // 16MB [4096][2048] bf16
  unsigned short* Qnn  = (unsigned short*)(ws + 24 * MB);   // 8MB
  unsigned short* Knn  = (unsigned short*)(ws + 32 * MB);   // 8MB
  float* zpart         = (float*)(ws + 40 * MB);            // 1MB [8][16][2048]
  float* rc            = (float*)(ws + 41 * MB);            // 128KB
  float* imp_part      = (float*)(ws + 42 * MB);            // 2MB [256][2048]
  unsigned short* xh   = (unsigned short*)(ws + 44 * MB);   // 4MB
  unsigned short* xl   = (unsigned short*)(ws + 48 * MB);   // 4MB
  unsigned short* w1Th = (unsigned short*)(ws + 52 * MB);   // 2MB each
  unsigned short* w1Tl = (unsigned short*)(ws + 54 * MB);
  unsigned short* w2Th = (unsigned short*)(ws + 56 * MB);
  unsigned short* w2Tl = (unsigned short*)(ws + 58 * MB);
  unsigned short* h1h  = (unsigned short*)(ws + 60 * MB);   // 4MB
  unsigned short* h1l  = (unsigned short*)(ws + 64 * MB);   // 4MB
  float* h2            = (float*)(ws + 68 * MB);            // 8MB

  dim3 tb(32, 8);
  k_prep<<<8192 + T_TOK, 256, 0, stream>>>(x, xh, xl, xproj, anw, xn);
  k_transpose_qk<<<dim3(AHX / 32, AHX / 32, 2), tb, 0, stream>>>(wq, wk, wqkT);

  // fused Q|K projection + per-head rmsnorm -> Qnn/Knn bf16
  k_gemm_qk<<<dim3(32, 16), 256, 0, stream>>>(xn, wqkT, bq, bk, qnw, knw, Qnn, Knn, AHX);

  // MLP weight prep
  k_transpose_w12<<<dim3(HIDX / 32, DIMX / 32, 2), tb, 0, stream>>>(w1, w2, w1Th, w1Tl, w2Th, w2Tl);

  // scores: denominators then per-tile importance partials
  k_z<<<dim3(16, NHEAD, 8), 256, 0, stream>>>(Qnn, Knn, zpart);
  k_rc<<<(NHEAD * T_TOK) / 256, 256, 0, stream>>>(zpart, rc);
  k_imp<<<dim3(16, NHEAD, 8), 256, 0, stream>>>(Qnn, Knn, rc, imp_part);

  // router MLP (split-bf16 fp32 emulation)
  k_gemm_mlp<1><<<dim3(HIDX / 64, T_TOK / 64), 256, 0, stream>>>(
      xh, xl, w1Th, w1Tl, b1, nullptr, h1h, h1l, HIDX, DIMX);
  k_gemm_mlp<2><<<dim3(HIDX / 64, T_TOK / 64), 256, 0, stream>>>(
      h1h, h1l, w2Th, w2Tl, b2, h2, nullptr, nullptr, HIDX, HIDX);

  // importance reduction + router top-k
  k_final<<<8 + T_TOK / 4, 256, 0, stream>>>(imp_part, h2, w3, b3, out);

  (void)in_sizes; (void)n_in; (void)out_size; (void)ws_size;
}

// Round 7
// 181.653 us; speedup vs baseline: 2.4930x; 1.0708x over previous
//
#include <hip/hip_runtime.h>

#define T_TOK 2048
#define DIMX  1024
#define AHX   2048
#define HIDX  1024
#define NEXP  8
#define NHEAD 16
#define HD    128

typedef unsigned short us;
typedef short bf16x8 __attribute__((ext_vector_type(8)));
typedef float f32x4  __attribute__((ext_vector_type(4)));

__device__ __forceinline__ us f2bf(float f){
  unsigned int u = __builtin_bit_cast(unsigned int, f);
  u += 0x7FFFu + ((u >> 16) & 1u);          // RNE
  return (us)(u >> 16);
}
__device__ __forceinline__ float bf2f(us h){
  unsigned int u = ((unsigned int)h) << 16;
  return __builtin_bit_cast(float, u);
}
__device__ __forceinline__ float gelu_exact(float x){
  return 0.5f * x * (1.0f + erff(x * 0.70710678118654752440f));
}
__device__ __forceinline__ void gload16(const us* g, us* l){
  __builtin_amdgcn_global_load_lds((const __attribute__((address_space(1))) unsigned int*)g,
                                   (__attribute__((address_space(3))) unsigned int*)l, 16, 0, 0);
}

// ------------- pre: split_cast(x) + rmsnorm(xproj) + transpose wq/wk + transpose/split w1/w2 ---
__global__ __launch_bounds__(256) void k_pre(const float* __restrict__ x,
                                             us* __restrict__ xh, us* __restrict__ xl,
                                             const float* __restrict__ xproj,
                                             const float* __restrict__ anw,
                                             us* __restrict__ xn,
                                             const float* __restrict__ wq,
                                             const float* __restrict__ wk,
                                             us* __restrict__ wqkT,
                                             const float* __restrict__ w1,
                                             const float* __restrict__ w2,
                                             us* __restrict__ w1h, us* __restrict__ w1l,
                                             us* __restrict__ w2h, us* __restrict__ w2l){
  __shared__ float tile[32][33];
  __shared__ float ps[4];
  int bx = blockIdx.x, t = threadIdx.x;
  if (bx < 8192){
    int i = bx * 256 + t;
    float v = x[i];
    us h = f2bf(v);
    xh[i] = h;
    xl[i] = f2bf(v - bf2f(h));
    return;
  }
  if (bx < 10240){
    int row = bx - 8192;
    const float* p = xproj + (size_t)row * AHX;
    float v[8];
    *(float4*)&v[0] = *(const float4*)(p + t * 8);
    *(float4*)&v[4] = *(const float4*)(p + t * 8 + 4);
    float s = 0.f;
    #pragma unroll
    for (int i = 0; i < 8; i++) s += v[i] * v[i];
    #pragma unroll
    for (int m = 1; m < 64; m <<= 1) s += __shfl_xor(s, m);
    if ((t & 63) == 0) ps[t >> 6] = s;
    __syncthreads();
    float tot = ps[0] + ps[1] + ps[2] + ps[3];
    float rs = rsqrtf(tot * (1.0f / AHX) + 1e-6f);
    #pragma unroll
    for (int i = 0; i < 8; i++)
      xn[(size_t)row * AHX + t * 8 + i] = f2bf(v[i] * rs * anw[t * 8 + i]);
    return;
  }
  int tx = t & 31, ty = t >> 5;   // 32x8
  if (bx < 18432){
    int sub = bx - 10240;
    const float* in = (sub >> 12) ? wk : wq;
    us* o = wqkT + (size_t)(sub >> 12) * AHX * AHX;
    int rem = sub & 4095;
    int tbx = (rem & 63) * 32, tby = (rem >> 6) * 32;
    #pragma unroll
    for (int i = 0; i < 32; i += 8)
      tile[ty + i][tx] = in[(size_t)(tby + ty + i) * AHX + tbx + tx];
    __syncthreads();
    #pragma unroll
    for (int i = 0; i < 32; i += 8)
      o[(size_t)(tbx + ty + i) * AHX + tby + tx] = f2bf(tile[tx][ty + i]);
    return;
  }
  {
    int sub = bx - 18432;
    const float* in = (sub >> 10) ? w2 : w1;
    us* oh = (sub >> 10) ? w2h : w1h;
    us* ol = (sub >> 10) ? w2l : w1l;
    int rem = sub & 1023;
    int tbx = (rem & 31) * 32, tby = (rem >> 5) * 32;
    #pragma unroll
    for (int i = 0; i < 32; i += 8)
      tile[ty + i][tx] = in[(size_t)(tby + ty + i) * HIDX + tbx + tx];
    __syncthreads();
    #pragma unroll
    for (int i = 0; i < 32; i += 8){
      float v = tile[tx][ty + i];
      us h = f2bf(v);
      size_t o = (size_t)(tbx + ty + i) * DIMX + tby + tx;
      oh[o] = h;
      ol[o] = f2bf(v - bf2f(h));
    }
  }
}

// ------- fused Q|K projection GEMM + per-head rmsnorm epilogue, 8 waves -------
__global__ __launch_bounds__(512) void k_gemm_qk(
    const us* __restrict__ A, const us* __restrict__ B,
    const float* __restrict__ bq, const float* __restrict__ bk,
    const float* __restrict__ qnw, const float* __restrict__ knw,
    us* __restrict__ Qnn, us* __restrict__ Knn, int K)
{
  __shared__ __align__(16) us sA[2][128 * 64];
  __shared__ __align__(16) us sB[2][128 * 64];
  __shared__ float sums[128][4];
  int tid = threadIdx.x;
  int bm = blockIdx.y * 128;
  int bnB = blockIdx.x * 128;
  int w = tid >> 6, l = tid & 63;
  int wm = (w >> 2) * 64, wn = (w & 3) * 32;
  int lhi = l >> 4, llo = l & 15;
  int srow = l >> 3;
  int scol = ((l & 7) ^ srow) * 8;
  int swz = llo & 7;

  const us* pA = &A[(size_t)(bm + w * 16 + srow) * K + scol];
  const us* pB = &B[(size_t)(bnB + w * 16 + srow) * K + scol];

  f32x4 acc[4][2] = {};

  #pragma unroll
  for (int i = 0; i < 2; i++){
    gload16(pA + (size_t)i * 8 * K, &sA[0][(w * 16 + i * 8) * 64]);
    gload16(pB + (size_t)i * 8 * K, &sB[0][(w * 16 + i * 8) * 64]);
  }
  __syncthreads();

  int cur = 0;
  for (int k0 = 0; k0 < K; k0 += 64){
    if (k0 + 64 < K){
      #pragma unroll
      for (int i = 0; i < 2; i++){
        gload16(pA + (size_t)i * 8 * K + k0 + 64, &sA[cur ^ 1][(w * 16 + i * 8) * 64]);
        gload16(pB + (size_t)i * 8 * K + k0 + 64, &sB[cur ^ 1][(w * 16 + i * 8) * 64]);
      }
    }
    bf16x8 af[2][4], bfr[2][2];
    #pragma unroll
    for (int kk = 0; kk < 2; kk++){
      int ca = ((kk * 4 + lhi) ^ swz) * 8;
      #pragma unroll
      for (int m = 0; m < 4; m++)
        af[kk][m] = *(const bf16x8*)&sA[cur][(wm + m * 16 + llo) * 64 + ca];
      #pragma unroll
      for (int n = 0; n < 2; n++)
        bfr[kk][n] = *(const bf16x8*)&sB[cur][(wn + n * 16 + llo) * 64 + ca];
    }
    #pragma unroll
    for (int kk = 0; kk < 2; kk++)
      #pragma unroll
      for (int m = 0; m < 4; m++)
        #pragma unroll
        for (int n = 0; n < 2; n++)
          acc[m][n] = __builtin_amdgcn_mfma_f32_16x16x32_bf16(af[kk][m], bfr[kk][n], acc[m][n], 0, 0, 0);
    __syncthreads();
    cur ^= 1;
  }

  bool isq = blockIdx.x < 16;
  const float* bias = isq ? bq : bk;
  const float* nw   = isq ? qnw : knw;
  us* outp = isq ? Qnn : Knn;
  int hcol0 = (blockIdx.x & 15) * 128;

  #pragma unroll
  for (int n = 0; n < 2; n++){
    float bv = bias[hcol0 + wn + n * 16 + llo];
    #pragma unroll
    for (int m = 0; m < 4; m++)
      #pragma unroll
      for (int j = 0; j < 4; j++) acc[m][n][j] += bv;
  }
  #pragma unroll
  for (int m = 0; m < 4; m++)
    #pragma unroll
    for (int j = 0; j < 4; j++){
      float p = 0.f;
      #pragma unroll
      for (int n = 0; n < 2; n++) p += acc[m][n][j] * acc[m][n][j];
      p += __shfl_xor(p, 1); p += __shfl_xor(p, 2);
      p += __shfl_xor(p, 4); p += __shfl_xor(p, 8);
      if (llo == 0) sums[wm + m * 16 + lhi * 4 + j][w & 3] = p;
    }
  __syncthreads();
  #pragma unroll
  for (int m = 0; m < 4; m++)
    #pragma unroll
    for (int j = 0; j < 4; j++){
      int row = wm + m * 16 + lhi * 4 + j;
      float rs = rsqrtf((sums[row][0] + sums[row][1] + sums[row][2] + sums[row][3]) * (1.0f / HD) + 1e-6f);
      #pragma unroll
      for (int n = 0; n < 2; n++){
        int col = wn + n * 16 + llo;
        outp[(size_t)(bm + row) * AHX + hcol0 + col] = f2bf(acc[m][n][j] * rs * nw[col]);
      }
    }
}

// -------- MLP GEMM: C[M,N] = A*B^T (+bias, epilogue), split-bf16 fp32 emulation ---------
template<int EPI>
__global__ __launch_bounds__(256) void k_gemm_mlp(
    const us* __restrict__ Ah_, const us* __restrict__ Al_,
    const us* __restrict__ Bh_, const us* __restrict__ Bl_,
    const float* __restrict__ bias,
    float* __restrict__ Cf, us* __restrict__ Ch, us* __restrict__ Cl,
    int N, int K)
{
  __shared__ __align__(16) us sAh[2][64 * 64], sAl[2][64 * 64];
  __shared__ __align__(16) us sBh[2][64 * 64], sBl[2][64 * 64];
  int tid = threadIdx.x;
  int bm = blockIdx.y * 64, bn = blockIdx.x * 64;
  int w = tid >> 6, l = tid & 63;
  int wm = (w >> 1) * 32, wn = (w & 1) * 32;
  int lhi = l >> 4, llo = l & 15;
  int srow = l >> 3;
  int scol = ((l & 7) ^ srow) * 8;
  int swz = llo & 7;

  const us* pAh = &Ah_[(size_t)(bm + w * 8 + srow) * K + scol];
  const us* pAl = &Al_[(size_t)(bm + w * 8 + srow) * K + scol];
  const us* pBh = &Bh_[(size_t)(bn + w * 8 + srow) * K + scol];
  const us* pBl = &Bl_[(size_t)(bn + w * 8 + srow) * K + scol];

  f32x4 acc[2][2] = {};

  auto stage = [&](int buf, int k0){
    #pragma unroll
    for (int i = 0; i < 2; i++){
      int rb = (i * 32 + w * 8) * 64;
      gload16(pAh + (size_t)i * 32 * K + k0, &sAh[buf][rb]);
      gload16(pAl + (size_t)i * 32 * K + k0, &sAl[buf][rb]);
      gload16(pBh + (size_t)i * 32 * K + k0, &sBh[buf][rb]);
      gload16(pBl + (size_t)i * 32 * K + k0, &sBl[buf][rb]);
    }
  };

  stage(0, 0);
  __syncthreads();

  int cur = 0;
  for (int k0 = 0; k0 < K; k0 += 64){
    if (k0 + 64 < K) stage(cur ^ 1, k0 + 64);
    bf16x8 ah[2][2], al[2][2], bh[2][2], bl[2][2];
    #pragma unroll
    for (int kk = 0; kk < 2; kk++){
      int ca = ((kk * 4 + lhi) ^ swz) * 8;
      #pragma unroll
      for (int m = 0; m < 2; m++){
        ah[kk][m] = *(const bf16x8*)&sAh[cur][(wm + m * 16 + llo) * 64 + ca];
        al[kk][m] = *(const bf16x8*)&sAl[cur][(wm + m * 16 + llo) * 64 + ca];
        bh[kk][m] = *(const bf16x8*)&sBh[cur][(wn + m * 16 + llo) * 64 + ca];
        bl[kk][m] = *(const bf16x8*)&sBl[cur][(wn + m * 16 + llo) * 64 + ca];
      }
    }
    #pragma unroll
    for (int kk = 0; kk < 2; kk++)
      #pragma unroll
      for (int m = 0; m < 2; m++)
        #pragma unroll
        for (int n = 0; n < 2; n++){
          acc[m][n] = __builtin_amdgcn_mfma_f32_16x16x32_bf16(ah[kk][m], bh[kk][n], acc[m][n], 0, 0, 0);
          acc[m][n] = __builtin_amdgcn_mfma_f32_16x16x32_bf16(ah[kk][m], bl[kk][n], acc[m][n], 0, 0, 0);
          acc[m][n] = __builtin_amdgcn_mfma_f32_16x16x32_bf16(al[kk][m], bh[kk][n], acc[m][n], 0, 0, 0);
        }
    __syncthreads();
    cur ^= 1;
  }

  #pragma unroll
  for (int m = 0; m < 2; m++)
    #pragma unroll
    for (int n = 0; n < 2; n++){
      int col = bn + wn + n * 16 + llo;
      float bv = bias[col];
      #pragma unroll
      for (int j = 0; j < 4; j++){
        int row = bm + wm + m * 16 + lhi * 4 + j;
        float v = acc[m][n][j] + bv;
        size_t off = (size_t)row * N + col;
        if constexpr (EPI == 1){
          float g = gelu_exact(v);
          us hh = f2bf(g);
          Ch[off] = hh;
          Cl[off] = f2bf(g - bf2f(hh));
        } else {
          Cf[off] = gelu_exact(v);
        }
      }
    }
}

// ---------------- scores denominator: 8 waves, 16 q-rows/wave ----------------
__global__ __launch_bounds__(512) void k_z(const us* __restrict__ Qn,
                                           const us* __restrict__ Kn,
                                           float* __restrict__ zpart){
  __shared__ __align__(16) us sK[2][128 * 128];
  int h = blockIdx.y;
  int qb = blockIdx.x * 128;
  int tid = threadIdx.x, w = tid >> 6, l = tid & 63;
  int lhi = l >> 4, llo = l & 15;
  int wq = qb + w * 16;
  const float scale = 0.08838834764831845f;

  auto stageK = [&](int buf, int kt){
    #pragma unroll
    for (int i = 0; i < 4; i++){
      int rb = w * 16 + i * 4;
      int r = rb + lhi;
      int c = ((llo ^ (r & 7))) * 8;
      gload16(&Kn[(size_t)(kt + r) * AHX + h * HD + c], &sK[buf][rb * 128]);
    }
  };

  bf16x8 qf[4];
  #pragma unroll
  for (int kk = 0; kk < 4; kk++)
    qf[kk] = *(const bf16x8*)&Qn[(size_t)(wq + llo) * AHX + h * HD + kk * 32 + lhi * 8];

  float rz[4] = {};
  int kt0 = blockIdx.z * 256;

  stageK(0, kt0);
  __syncthreads();

  #pragma unroll
  for (int t = 0; t < 2; t++){
    if (t == 0) stageK(1, kt0 + 128);
    f32x4 acc[8] = {};
    #pragma unroll
    for (int n = 0; n < 8; n++){
      int row = n * 16 + llo;
      #pragma unroll
      for (int kk = 0; kk < 4; kk++){
        bf16x8 kf = *(const bf16x8*)&sK[t][row * 128 + ((kk * 32 + lhi * 8) ^ ((llo & 7) << 3))];
        acc[n] = __builtin_amdgcn_mfma_f32_16x16x32_bf16(qf[kk], kf, acc[n], 0, 0, 0);
      }
    }
    #pragma unroll
    for (int j = 0; j < 4; j++){
      float s = 0.f;
      #pragma unroll
      for (int n = 0; n < 8; n++) s += __expf(acc[n][j] * scale);
      rz[j] += s;
    }
    if (t == 0) __syncthreads();
  }
  #pragma unroll
  for (int j = 0; j < 4; j++){
    float s = rz[j];
    s += __shfl_xor(s, 1); s += __shfl_xor(s, 2);
    s += __shfl_xor(s, 4); s += __shfl_xor(s, 8);
    if (llo == 0){
      int row = wq + lhi * 4 + j;
      zpart[(size_t)blockIdx.z * (NHEAD * T_TOK) + h * T_TOK + row] = s;
    }
  }
}

// ---------------- importance partials: 8 waves, inline rc gather ----------------
__global__ __launch_bounds__(512) void k_imp(const us* __restrict__ Qn,
                                             const us* __restrict__ Kn,
                                             const float* __restrict__ zpart,
                                             float* __restrict__ imp_part){
  __shared__ __align__(16) us sK[2][128 * 128];
  __shared__ float simp[8][128];
  int h = blockIdx.y;
  int qb = blockIdx.x * 128;
  int kt0 = blockIdx.z * 256;
  int tid = threadIdx.x, w = tid >> 6, l = tid & 63;
  int lhi = l >> 4, llo = l & 15;
  int wq = qb + w * 16;
  const float scale = 0.08838834764831845f;

  auto stageK = [&](int buf, int kt){
    #pragma unroll
    for (int i = 0; i < 4; i++){
      int rb = w * 16 + i * 4;
      int r = rb + lhi;
      int c = ((llo ^ (r & 7))) * 8;
      gload16(&Kn[(size_t)(kt + r) * AHX + h * HD + c], &sK[buf][rb * 128]);
    }
  };

  bf16x8 qf[4];
  float rcv[4];
  #pragma unroll
  for (int kk = 0; kk < 4; kk++)
    qf[kk] = *(const bf16x8*)&Qn[(size_t)(wq + llo) * AHX + h * HD + kk * 32 + lhi * 8];
  #pragma unroll
  for (int j = 0; j < 4; j++){
    int row = wq + lhi * 4 + j;
    float zs = 0.f;
    #pragma unroll
    for (int p = 0; p < 8; p++) zs += zpart[(size_t)p * (NHEAD * T_TOK) + h * T_TOK + row];
    rcv[j] = 1.0f / ((float)NHEAD * zs);
  }

  stageK(0, kt0);
  __syncthreads();

  #pragma unroll
  for (int t = 0; t < 2; t++){
    if (t == 0) stageK(1, kt0 + 128);
    f32x4 acc[8] = {};
    #pragma unroll
    for (int n = 0; n < 8; n++){
      int row = n * 16 + llo;
      #pragma unroll
      for (int kk = 0; kk < 4; kk++){
        bf16x8 kf = *(const bf16x8*)&sK[t][row * 128 + ((kk * 32 + lhi * 8) ^ ((llo & 7) << 3))];
        acc[n] = __builtin_amdgcn_mfma_f32_16x16x32_bf16(qf[kk], kf, acc[n], 0, 0, 0);
      }
    }
    #pragma unroll
    for (int n = 0; n < 8; n++){
      float s = 0.f;
      #pragma unroll
      for (int j = 0; j < 4; j++)
        s += __expf(acc[n][j] * scale) * rcv[j];
      s += __shfl_xor(s, 16);
      s += __shfl_xor(s, 32);
      if (l < 16) simp[w][n * 16 + l] = s;
    }
    __syncthreads();
    if (tid < 128){
      float tot = 0.f;
      #pragma unroll
      for (int ww = 0; ww < 8; ww++) tot += simp[ww][tid];
      imp_part[((size_t)blockIdx.x * NHEAD + h) * T_TOK + kt0 + t * 128 + tid] = tot;
    }
    __syncthreads();
  }
}

// ---------------- final: impred [blocks 0..7] + router [8..519] ----------------
__global__ __launch_bounds__(256) void k_final(const float* __restrict__ imp_part,
                                               const float* __restrict__ h2,
                                               const float* __restrict__ w3,
                                               const float* __restrict__ b3,
                                               float* __restrict__ out){
  if (blockIdx.x < 8){
    int col = blockIdx.x * 256 + threadIdx.x;
    float s = 0.f;
    for (int r = 0; r < 256; r++) s += imp_part[(size_t)r * T_TOK + col];
    out[2 * T_TOK + col] = s;
    return;
  }
  int t = (blockIdx.x - 8) * 4 + (threadIdx.x >> 6);
  int l = threadIdx.x & 63;
  const float* hp = h2 + (size_t)t * HIDX;
  float acc[NEXP] = {};
  for (int i = l; i < HIDX; i += 64){
    float hv = hp[i];
    const float* wr = w3 + (size_t)i * NEXP;
    #pragma unroll
    for (int e = 0; e < NEXP; e++) acc[e] = fmaf(hv, wr[e], acc[e]);
  }
  #pragma unroll
  for (int mk = 1; mk < 64; mk <<= 1)
    #pragma unroll
    for (int e = 0; e < NEXP; e++) acc[e] += __shfl_xor(acc[e], mk);
  if (l == 0){
    float lg[NEXP], mx = -__builtin_inff();
    #pragma unroll
    for (int e = 0; e < NEXP; e++){ lg[e] = acc[e] + b3[e]; mx = fmaxf(mx, lg[e]); }
    float Z = 0.f, p[NEXP];
    #pragma unroll
    for (int e = 0; e < NEXP; e++){ p[e] = expf(lg[e] - mx); Z += p[e]; }
    float invZ = 1.0f / Z;
    #pragma unroll
    for (int e = 0; e < NEXP; e++) p[e] *= invZ;
    float gs[4];
    #pragma unroll
    for (int g = 0; g < 4; g++) gs[g] = fmaxf(p[2 * g], p[2 * g + 1]);
    int g1 = 0;
    #pragma unroll
    for (int g = 1; g < 4; g++) if (gs[g] > gs[g1]) g1 = g;
    int g2 = -1; float g2v = -__builtin_inff();
    #pragma unroll
    for (int g = 0; g < 4; g++) if (g != g1 && gs[g] > g2v){ g2v = gs[g]; g2 = g; }
    int best = 0; float bv = -__builtin_inff();
    #pragma unroll
    for (int e = 0; e < NEXP; e++){
      int g = e >> 1;
      if ((g == g1 || g == g2) && p[e] > bv){ bv = p[e]; best = e; }
    }
    out[t]         = bv;            // ROUTE_SCALE = 1.0
    out[T_TOK + t] = (float)best;   // idx as float
  }
}

// ---------------- driver ----------------
extern "C" void kernel_launch(void* const* d_in, const int* in_sizes, int n_in,
                              void* d_out, int out_size, void* d_ws, size_t ws_size,
                              hipStream_t stream){
  const float* x     = (const float*)d_in[0];
  const float* xproj = (const float*)d_in[1];
  const float* anw   = (const float*)d_in[2];
  const float* wq    = (const float*)d_in[3];
  const float* bq    = (const float*)d_in[4];
  const float* wk    = (const float*)d_in[5];
  const float* bk    = (const float*)d_in[6];
  const float* qnw   = (const float*)d_in[7];
  const float* knw   = (const float*)d_in[8];
  const float* w1    = (const float*)d_in[9];
  const float* b1    = (const float*)d_in[10];
  const float* w2    = (const float*)d_in[11];
  const float* b2    = (const float*)d_in[12];
  const float* w3    = (const float*)d_in[13];
  const float* b3    = (const float*)d_in[14];
  float* out = (float*)d_out;

  char* ws = (char*)d_ws;
  const size_t MB = 1024 * 1024;
  us* xn      = (us*)(ws);             // 8MB  [T][AHX] bf16
  us* wqkT    = (us*)(ws + 8 * MB);    // 16MB [4096][2048] bf16
  us* Qnn     = (us*)(ws + 24 * MB);   // 8MB
  us* Knn     = (us*)(ws + 32 * MB);   // 8MB
  float* zpart    = (float*)(ws + 40 * MB);  // 1MB [8][16][2048]
  float* imp_part = (float*)(ws + 42 * MB);  // 2MB [256][2048]
  us* xh      = (us*)(ws + 44 * MB);   // 4MB
  us* xl      = (us*)(ws + 48 * MB);   // 4MB
  us* w1Th    = (us*)(ws + 52 * MB);   // 2MB each
  us* w1Tl    = (us*)(ws + 54 * MB);
  us* w2Th    = (us*)(ws + 56 * MB);
  us* w2Tl    = (us*)(ws + 58 * MB);
  us* h1h     = (us*)(ws + 60 * MB);   // 4MB
  us* h1l     = (us*)(ws + 64 * MB);   // 4MB
  float* h2   = (float*)(ws + 68 * MB);// 8MB

  // all input prep in one kernel
  k_pre<<<20480, 256, 0, stream>>>(x, xh, xl, xproj, anw, xn,
                                   wq, wk, wqkT, w1, w2, w1Th, w1Tl, w2Th, w2Tl);

  // fused Q|K projection + per-head rmsnorm -> Qnn/Knn bf16 (8-wave blocks)
  k_gemm_qk<<<dim3(32, 16), 512, 0, stream>>>(xn, wqkT, bq, bk, qnw, knw, Qnn, Knn, AHX);

  // scores: denominators then per-tile importance partials (rc inline)
  k_z<<<dim3(16, NHEAD, 8), 512, 0, stream>>>(Qnn, Knn, zpart);
  k_imp<<<dim3(16, NHEAD, 8), 512, 0, stream>>>(Qnn, Knn, zpart, imp_part);

  // router MLP (split-bf16 fp32 emulation)
  k_gemm_mlp<1><<<dim3(HIDX / 64, T_TOK / 64), 256, 0, stream>>>(
      xh, xl, w1Th, w1Tl, b1, nullptr, h1h, h1l, HIDX, DIMX);
  k_gemm_mlp<2><<<dim3(HIDX / 64, T_TOK / 64), 256, 0, stream>>>(
      h1h, h1l, w2Th, w2Tl, b2, h2, nullptr, nullptr, HIDX, HIDX);

  // importance reduction + router top-k
  k_final<<<8 + T_TOK / 4, 256, 0, stream>>>(imp_part, h2, w3, b3, out);

  (void)in_sizes; (void)n_in; (void)out_size; (void)ws_size;
}